// Round 12
// baseline (490.747 us; speedup 1.0000x reference)
//
#include <hip/hip_runtime.h>
#include <hip/hip_bf16.h>

#define EP 60000
#define NE 300000
#define M2 120000
#define NIN 50000
#define NOUT 50000
#define PAD 65
#define NIMG 49

typedef __bf16 b16x8 __attribute__((ext_vector_type(8)));
typedef float f32x4 __attribute__((ext_vector_type(4)));
typedef unsigned short us8 __attribute__((ext_vector_type(8)));
typedef unsigned short us4 __attribute__((ext_vector_type(4)));

// exact-erf GELU — used in k_ef1 (feeds the Gram/softmax path; keep exact)
__device__ __forceinline__ float gelu_f(float x) {
    return 0.5f * x * (1.0f + erff(x * 0.70710678118654752440f));
}

// fast erf-GELU (A&S 7.1.26, |eps_erf|<=1.5e-7) — SAFE ONLY outside the Gram path
__device__ __forceinline__ float gelu_fast(float x) {
    float ax = fabsf(x) * 0.70710678118654752440f;
    float t = __builtin_amdgcn_rcpf(fmaf(0.3275911f, ax, 1.0f));
    float y = fmaf(fmaf(fmaf(fmaf(1.061405429f, t, -1.453152027f), t, 1.421413741f),
                        t, -0.284496736f), t, 0.254829592f) * t;
    float e = __expf(-ax * ax);
    float erf = fmaf(-y, e, 1.0f);
    return 0.5f * x * (1.0f + copysignf(erf, x));
}

__device__ __forceinline__ unsigned short bfhi(float f) {
    unsigned int u = __float_as_uint(f);
    u += 0x7FFFu + ((u >> 16) & 1u);   // RNE
    return (unsigned short)(u >> 16);
}

// RNE split (reconstruct err 2^-18) — used where the Gram path consumes the result
__device__ __forceinline__ void split2(float f, unsigned short& h, unsigned short& l) {
    h = bfhi(f);
    float fh = __uint_as_float(((unsigned int)h) << 16);
    l = bfhi(f - fh);
}

// fast truncating split (reconstruct err 2^-17, unbiased residual) — k_fuse interior
__device__ __forceinline__ void split2f(float f, unsigned short& h, unsigned short& l) {
    unsigned int u = __float_as_uint(f);
    h = (unsigned short)(u >> 16);
    float fh = __uint_as_float(u & 0xFFFF0000u);
    l = bfhi(f - fh);
}

__device__ __forceinline__ float bf2f(unsigned short u) {
    return __uint_as_float(((unsigned int)u) << 16);
}

// swizzled ushort-index into a [row][64] bf16 plane (XOR-swizzle, 8-ushort cells)
__device__ __forceinline__ int xidx(int row, int col) {
    return (row * 64 + col) ^ ((row & 7) << 3);
}

__device__ __forceinline__ b16x8 ldfrag(const unsigned short* p, int id) {
    return __builtin_bit_cast(b16x8, *(const us8*)(p + id));
}

__device__ __forceinline__ f32x4 MF(b16x8 a, b16x8 b, f32x4 c) {
    return __builtin_amdgcn_mfma_f32_16x16x32_bf16(a, b, c, 0, 0, 0);
}

__device__ __forceinline__ void zacc(f32x4 a[2][2]) {
#pragma unroll
    for (int i = 0; i < 2; ++i)
#pragma unroll
        for (int j = 0; j < 2; ++j) a[i][j] = (f32x4){0.f, 0.f, 0.f, 0.f};
}

__device__ __forceinline__ void gll16(const unsigned short* g, unsigned short* l) {
    __builtin_amdgcn_global_load_lds((const __attribute__((address_space(1))) void*)g,
                                     (__attribute__((address_space(3))) void*)l, 16, 0, 0);
}

// stage a prepped 16KB weight image via async global->LDS (512 threads: 2 issues each)
// RACE NOTE (R7/R8 lesson): stageWimg must be drained by __syncthreads() BEFORE any
// wave reads WHL; the pipelined ping-pong variant raced (NaN). Keep this pattern.
__device__ __forceinline__ void stageWimg(const unsigned short* __restrict__ img,
                                          unsigned short* __restrict__ WHL, int tid) {
    int w = tid >> 6, lane = tid & 63;
#pragma unroll
    for (int j = 0; j < 2; ++j)
        gll16(img + w * 1024 + j * 512 + lane * 8, WHL + w * 1024 + j * 512);
}

// stage 128 contiguous pre-split rows [row][hi0..63|lo0..63] -> swizzled planes (512 thr)
__device__ __forceinline__ void stageX_rows(const unsigned short* __restrict__ src, int rmax,
                                            unsigned short* __restrict__ XH, unsigned short* __restrict__ XL,
                                            int tid) {
#pragma unroll
    for (int q = 0; q < 4; ++q) {
        int f = q * 512 + tid;
        int row = f >> 4, cc = f & 15;
        int rc = min(row, rmax - 1);
        us8 v = *(const us8*)(src + (size_t)rc * 128 + cc * 8);
        unsigned short* pl = (cc < 8) ? XH : XL;
        *(us8*)(pl + xidx(row, (cc & 7) * 8)) = v;
    }
}

// stage pick rows: type==0 -> compute volt[idx]*nf1W+nf1b on the fly (4B read),
//                  type==1 -> gather pre-split NFO row (256B)
__device__ __forceinline__ void stageX_pick(const int* __restrict__ tp, const int* __restrict__ ix, int base,
                                            int rmax, const float* __restrict__ volt,
                                            const unsigned short* __restrict__ nfo,
                                            const float* __restrict__ sNW, const float* __restrict__ sNB,
                                            unsigned short* __restrict__ XH, unsigned short* __restrict__ XL,
                                            int tid) {
#pragma unroll
    for (int q = 0; q < 4; ++q) {
        int f = q * 512 + tid;
        int row = f >> 4, cc = f & 15;
        int rc = min(row, rmax - 1);
        int ty = tp[base + rc];
        int idx = ix[base + rc];
        int c8 = (cc & 7) * 8;
        unsigned short* pl = (cc < 8) ? XH : XL;
        us8 v;
        if (ty == 0) {
            float vv = volt[idx];
#pragma unroll
            for (int j = 0; j < 8; ++j) {
                float x = fmaf(vv, sNW[c8 + j], sNB[c8 + j]);
                unsigned short h, l;
                split2f(x, h, l);
                v[j] = (cc < 8) ? h : l;
            }
        } else {
            v = *(const us8*)(nfo + (size_t)idx * 128 + cc * 8);
        }
        *(us8*)(pl + xidx(row, c8)) = v;
    }
}

// 8-wave col-split gemm: wave (wr,wc) computes rows [wr*32,+32) x cols [wc*32,+32)
__device__ __forceinline__ void mf_gemm64(const unsigned short* __restrict__ XH, const unsigned short* __restrict__ XL,
                                          const unsigned short* __restrict__ WH, const unsigned short* __restrict__ WL,
                                          f32x4 acc[2][2], int wr, int wc, int lane) {
    int lr = lane & 15, g = lane >> 4;
#pragma unroll
    for (int kk = 0; kk < 2; ++kk) {
        int k0 = kk * 32 + g * 8;
        b16x8 ah[2], al[2];
#pragma unroll
        for (int rt = 0; rt < 2; ++rt) {
            int id = xidx(wr * 32 + rt * 16 + lr, k0);
            ah[rt] = ldfrag(XH, id);
            al[rt] = ldfrag(XL, id);
        }
#pragma unroll
        for (int t = 0; t < 2; ++t) {
            int id = xidx((wc * 2 + t) * 16 + lr, k0);
            b16x8 bh = ldfrag(WH, id), bl = ldfrag(WL, id);
#pragma unroll
            for (int rt = 0; rt < 2; ++rt) {
                acc[rt][t] = MF(ah[rt], bh, acc[rt][t]);
                acc[rt][t] = MF(ah[rt], bl, acc[rt][t]);
                acc[rt][t] = MF(al[rt], bh, acc[rt][t]);
            }
        }
    }
}

// acc + bias (+gelu) -> X planes (MUST be barrier-protected: waves share rows)
template <bool GELU, bool FAST>
__device__ __forceinline__ void writeback(f32x4 acc[2][2], const float* __restrict__ sb,
                                          unsigned short* __restrict__ XH, unsigned short* __restrict__ XL,
                                          int wr, int wc, int lane) {
    int lr = lane & 15, g = lane >> 4;
#pragma unroll
    for (int rt = 0; rt < 2; ++rt)
#pragma unroll
        for (int t = 0; t < 2; ++t)
#pragma unroll
            for (int r = 0; r < 4; ++r) {
                int row = wr * 32 + rt * 16 + g * 4 + r;
                int col = (wc * 2 + t) * 16 + lr;
                float v = acc[rt][t][r] + sb[col];
                if (GELU) v = FAST ? gelu_fast(v) : gelu_f(v);
                unsigned short h, l;
                if (FAST) split2f(v, h, l); else split2(v, h, l);
                int id = xidx(row, col);
                XH[id] = h; XL[id] = l;
            }
}

// plain cached stores (NT stores regressed WRITE_SIZE +77MB in R11 — do not reintroduce)
__device__ __forceinline__ void writeglob(f32x4 acc[2][2], const float* __restrict__ sb,
                                          float* __restrict__ dst, int rmax, int wr, int wc, int lane) {
    int lr = lane & 15, g = lane >> 4;
#pragma unroll
    for (int rt = 0; rt < 2; ++rt)
#pragma unroll
        for (int t = 0; t < 2; ++t)
#pragma unroll
            for (int r = 0; r < 4; ++r) {
                int row = wr * 32 + rt * 16 + g * 4 + r;
                if (row < rmax) {
                    int col = (wc * 2 + t) * 16 + lr;
                    dst[(size_t)row * 64 + col] = acc[rt][t][r] + sb[col];
                }
            }
}

// acc + bias -> split bf16 table rows [row][hi|lo] (RNE: feeds Gram path)
__device__ __forceinline__ void writeglob_split(f32x4 acc[2][2], const float* __restrict__ sb,
                                                unsigned short* __restrict__ dst, int rmax,
                                                int wr, int wc, int lane) {
    int lr = lane & 15, g = lane >> 4;
#pragma unroll
    for (int rt = 0; rt < 2; ++rt)
#pragma unroll
        for (int t = 0; t < 2; ++t)
#pragma unroll
            for (int r = 0; r < 4; ++r) {
                int row = wr * 32 + rt * 16 + g * 4 + r;
                if (row < rmax) {
                    int col = (wc * 2 + t) * 16 + lr;
                    float v = acc[rt][t][r] + sb[col];
                    unsigned short h, l;
                    split2(v, h, l);
                    dst[(size_t)row * 128 + col] = h;
                    dst[(size_t)row * 128 + 64 + col] = l;
                }
            }
}

__global__ void k_zero(int* __restrict__ p, int n) {
    int i = blockIdx.x * 256 + threadIdx.x;
    if (i < n) p[i] = 0;
}

// ---------------- prep: split+transpose+swizzle all 49 weight mats ----------------
__global__ __launch_bounds__(256) void k_prepw(
    const float* __restrict__ e1W2, const float* __restrict__ e1W3,
    const float* __restrict__ mW1, const float* __restrict__ mW2,
    const float* __restrict__ mW3, const float* __restrict__ mW4,
    const float* __restrict__ rW1, const float* __restrict__ rW2,
    const float* __restrict__ rW3, const float* __restrict__ rW4,
    const float* __restrict__ sw1, const float* __restrict__ sw2,
    const float* __restrict__ sw3, const float* __restrict__ sw4,
    const float* __restrict__ scw, unsigned short* __restrict__ wimg) {
    int b = blockIdx.x, tid = threadIdx.x;
    const float* src;
    if (b < 5) src = e1W2 + b * 4096;
    else if (b < 10) src = e1W3 + (b - 5) * 4096;
    else if (b < 20) src = mW1 + (b - 10) * 4096;
    else if (b < 22) src = mW2 + (b - 20) * 4096;
    else if (b < 24) src = mW3 + (b - 22) * 4096;
    else if (b < 26) src = mW4 + (b - 24) * 4096;
    else if (b < 35) src = rW1 + (b - 26) * 4096;
    else if (b < 38) src = rW2 + (b - 35) * 4096;
    else if (b < 41) src = rW3 + (b - 38) * 4096;
    else if (b < 44) src = rW4 + (b - 41) * 4096;
    else if (b == 44) src = sw1;
    else if (b == 45) src = sw2;
    else if (b == 46) src = sw3;
    else if (b == 47) src = sw4;
    else src = scw;
    unsigned short* dst = wimg + (size_t)b * 8192;
#pragma unroll
    for (int q = 0; q < 4; ++q) {
        int flat = q * 256 + tid;
        int k = flat >> 4, n4 = (flat & 15) * 4;
        float4 v = ((const float4*)src)[flat];
        float vv[4] = {v.x, v.y, v.z, v.w};
#pragma unroll
        for (int i = 0; i < 4; ++i) {
            unsigned short h, l;
            split2(vv[i], h, l);
            int id = xidx(n4 + i, k);
            dst[id] = h;
            dst[4096 + id] = l;
        }
    }
}

// ---------------- ef1: per-type 3-layer MLP -> split table (8-wave) ----------------
// Feeds Gram/softmax: exact gelu + RNE splits throughout.
__global__ __launch_bounds__(512, 4) void k_ef1(
    const float* __restrict__ dp,
    const float* __restrict__ w1, const float* __restrict__ b1,
    const float* __restrict__ b2, const float* __restrict__ b3,
    const unsigned short* __restrict__ wimg,
    unsigned short* __restrict__ e1s) {
    __shared__ unsigned short XH[8192], XL[8192], WHL[8192];
    __shared__ float sb[2][64], sW1[64], sB1[64];
    const int tid = threadIdx.x, ty = blockIdx.y;
    const int i0 = blockIdx.x * 128;
    const int rmax = min(128, EP - i0);
    const int w = tid >> 6, lane = tid & 63;
    const int wr = w >> 1, wc = w & 1;
    const size_t row0 = (size_t)ty * EP + i0;

    stageWimg(wimg + (size_t)ty * 8192, WHL, tid);
    if (tid < 64) { sW1[tid] = w1[ty * 64 + tid]; sB1[tid] = b1[ty * 64 + tid]; }
    else if (tid < 128) sb[0][tid - 64] = b2[ty * 64 + tid - 64];
    else if (tid < 192) sb[1][tid - 128] = b3[ty * 64 + tid - 128];
    __syncthreads();
    // L1: gelu(d*w1+b1) straight into planes
#pragma unroll
    for (int q = 0; q < 4; ++q) {
        int flat = q * 512 + tid;
        int rr = flat >> 4, cc = flat & 15;
        int rc = min(rr, rmax - 1);
        float d = dp[(size_t)ty * EP + i0 + rc];
        us4 h, l;
#pragma unroll
        for (int j = 0; j < 4; ++j) {
            int c = cc * 4 + j;
            float v = gelu_f(fmaf(d, sW1[c], sB1[c]));
            unsigned short hh, ll;
            split2(v, hh, ll);
            h[j] = hh; l[j] = ll;
        }
        *(us4*)(XH + xidx(rr, cc * 4)) = h;
        *(us4*)(XL + xidx(rr, cc * 4)) = l;
    }
    __syncthreads();
    f32x4 acc[2][2];
    zacc(acc); mf_gemm64(XH, XL, WHL, WHL + 4096, acc, wr, wc, lane);
    __syncthreads();
    writeback<true, false>(acc, sb[0], XH, XL, wr, wc, lane);
    stageWimg(wimg + (size_t)(5 + ty) * 8192, WHL, tid);
    __syncthreads();
    zacc(acc); mf_gemm64(XH, XL, WHL, WHL + 4096, acc, wr, wc, lane);
    writeglob_split(acc, sb[1], e1s + row0 * 128, rmax, wr, wc, lane);
}

// ---------------- f32 VALU helpers ----------------
__device__ __forceinline__ void zero16(float* a) {
#pragma unroll
    for (int q = 0; q < 16; ++q) a[q] = 0.f;
}

// ---------------- G = ef1^T @ ef1 ----------------
__global__ __launch_bounds__(256) void k_gram(const unsigned short* __restrict__ e1s, float* __restrict__ G) {
    __shared__ float4 rows[512];
    const int tid = threadIdx.x;
    const int i = tid >> 4, j = tid & 15;
    float4 accs[4];
#pragma unroll
    for (int p = 0; p < 4; ++p) accs[p] = make_float4(0, 0, 0, 0);
    int nb = gridDim.x;
    int per = (NE + nb - 1) / nb;
    int r0 = blockIdx.x * per;
    int r1 = min(r0 + per, NE);
    for (int rb = r0; rb < r1; rb += 32) {
        __syncthreads();
#pragma unroll
        for (int q = 0; q < 2; ++q) {
            int f = q * 256 + tid;
            int row = rb + (f >> 4), ch = f & 15;
            if (row < r1) {
                const unsigned short* rp = e1s + (size_t)row * 128;
                us4 h = *(const us4*)(rp + ch * 4);
                us4 l = *(const us4*)(rp + 64 + ch * 4);
                rows[f] = make_float4(bf2f(h[0]) + bf2f(l[0]), bf2f(h[1]) + bf2f(l[1]),
                                      bf2f(h[2]) + bf2f(l[2]), bf2f(h[3]) + bf2f(l[3]));
            } else {
                rows[f] = make_float4(0, 0, 0, 0);
            }
        }
        __syncthreads();
#pragma unroll 4
        for (int rr = 0; rr < 32; ++rr) {
            float4 a = rows[rr * 16 + i];
            float4 b = rows[rr * 16 + j];
            float ap[4] = {a.x, a.y, a.z, a.w};
#pragma unroll
            for (int p = 0; p < 4; ++p) {
                accs[p].x = fmaf(ap[p], b.x, accs[p].x);
                accs[p].y = fmaf(ap[p], b.y, accs[p].y);
                accs[p].z = fmaf(ap[p], b.z, accs[p].z);
                accs[p].w = fmaf(ap[p], b.w, accs[p].w);
            }
        }
    }
#pragma unroll
    for (int p = 0; p < 4; ++p) {
        int row = (i * 4 + p) * 64 + j * 4;
        atomicAdd(&G[row + 0], accs[p].x);
        atomicAdd(&G[row + 1], accs[p].y);
        atomicAdd(&G[row + 2], accs[p].z);
        atomicAdd(&G[row + 3], accs[p].w);
    }
}

// ---------------- CSR build ----------------
__global__ void k_hist(const int* __restrict__ dst_t, const int* __restrict__ dst_n, int* __restrict__ hist) {
    int e = blockIdx.x * 256 + threadIdx.x;
    if (e < NE && dst_t[e] == 1) atomicAdd(&hist[dst_n[e]], 1);
}

__global__ __launch_bounds__(1024) void k_scan(const int* __restrict__ hist, int* __restrict__ row_start) {
    __shared__ int part[1024];
    const int tid = threadIdx.x;
    const int chunk = (NOUT + 1023) / 1024;
    int lo = tid * chunk, hi = min(lo + chunk, NOUT);
    int s = 0;
    for (int i = lo; i < hi; ++i) s += hist[i];
    part[tid] = s;
    __syncthreads();
    for (int off = 1; off < 1024; off <<= 1) {
        int v = part[tid];
        int add = (tid >= off) ? part[tid - off] : 0;
        __syncthreads();
        part[tid] = v + add;
        __syncthreads();
    }
    int base = (tid == 0) ? 0 : part[tid - 1];
    for (int i = lo; i < hi; ++i) { row_start[i] = base; base += hist[i]; }
    if (lo < NOUT && hi == NOUT) row_start[NOUT] = base;
}

__global__ void k_scatter(const int* __restrict__ dst_t, const int* __restrict__ dst_n,
                          const int* __restrict__ row_start, int* __restrict__ cursor, int* __restrict__ elist) {
    int e = blockIdx.x * 256 + threadIdx.x;
    if (e < NE && dst_t[e] == 1) {
        int n = dst_n[e];
        int pos = atomicAdd(&cursor[n], 1);
        elist[row_start[n] + pos] = e;
    }
}

// ---------------- fused logits + segment softmax + weighted sum ----------------
// Per edge: one 256B e1s gather serves BOTH the logit (x.G matvec vs LDS-resident G)
// and the weighted sum. Eliminates the lgc buffer (76MB round-trip) + a kernel.
__global__ __launch_bounds__(256) void k_att(const unsigned short* __restrict__ e1s,
                                             const float* __restrict__ G,
                                             const int* __restrict__ row_start,
                                             const int* __restrict__ elist,
                                             unsigned short* __restrict__ nfo) {
    __shared__ float sG[4096];
    __shared__ float xrow[4][64];
    const int tid = threadIdx.x;
    {   // stage G (16KB, L2-hot) cooperatively
        const float4* g4 = (const float4*)G;
        float4* l4 = (float4*)sG;
#pragma unroll
        for (int q = 0; q < 4; ++q) l4[q * 256 + tid] = g4[q * 256 + tid];
    }
    __syncthreads();
    const int wv = tid >> 6, lane = tid & 63;
    int n = blockIdx.x * 4 + wv;
    if (n >= NOUT) return;
    int s = row_start[n], t = row_start[n + 1];
    float m = -3.0e38f, den = 0.f, num = 0.f;
    for (int i = s; i < t; ++i) {
        int eid = elist[i];
        float e = bf2f(e1s[(size_t)eid * 128 + lane]) + bf2f(e1s[(size_t)eid * 128 + 64 + lane]);
        xrow[wv][lane] = e;               // wave-private row; in-wave LDS ordering
        __builtin_amdgcn_wave_barrier();  // compile-time fence: writes before reads
        float lg = 0.f;
#pragma unroll 8
        for (int k = 0; k < 64; ++k)
            lg = fmaf(xrow[wv][k], sG[k * 64 + lane], lg);   // broadcast x_k, lane=col
        float mn = fmaxf(m, lg);
        float sc = __expf(m - mn);
        float ex = __expf(lg - mn);
        den = fmaf(den, sc, ex);
        num = fmaf(num, sc, ex * e);
        m = mn;
        __builtin_amdgcn_wave_barrier();  // keep next iter's write after this iter's reads
    }
    float v = (t > s) ? num / den : 0.f;
    unsigned short h, l;
    split2(v, h, l);
    nfo[(size_t)n * 128 + lane] = h;
    nfo[(size_t)n * 128 + 64 + lane] = l;
}

// ---------------- fused: self-L1 front-loaded + ef2 chain + self chain + score -> out ----------------
// Conservative barrier discipline (R6-verified). e1s read ONCE (prologue); self-L1 (accS)
// runs on those planes before the ef2 channel loop overwrites them. FAST numerics
// (approx gelu, truncating split) are safe here: this kernel is outside the Gram path.
__global__ __launch_bounds__(512, 4) void k_fuse(
    const unsigned short* __restrict__ e1s, const unsigned short* __restrict__ nfo,
    const unsigned short* __restrict__ wimg, const float* __restrict__ volt,
    const int* __restrict__ src_t, const int* __restrict__ src_n,
    const int* __restrict__ dst_t, const int* __restrict__ dst_n,
    const int* __restrict__ vg_t, const int* __restrict__ vg_i,
    const int* __restrict__ vb_t, const int* __restrict__ vb_i,
    const float* __restrict__ nf1W, const float* __restrict__ nf1b,
    const float* __restrict__ mb1, const float* __restrict__ mb2,
    const float* __restrict__ mb3, const float* __restrict__ mb4,
    const float* __restrict__ rb1, const float* __restrict__ rb2,
    const float* __restrict__ rb3, const float* __restrict__ rb4,
    const float* __restrict__ selb1, const float* __restrict__ selb2,
    const float* __restrict__ selb3, const float* __restrict__ selb4,
    const float* __restrict__ scb, float* __restrict__ out) {
    __shared__ unsigned short XH[8192], XL[8192], WHL[8192];
    __shared__ float sb[3][64], sNW[64], sNB[64];
    const int tid = threadIdx.x;
    const int gy = blockIdx.y;
    const bool mos = gy < 2;
    const int ty = mos ? gy : gy - 2;
    const int nch = mos ? 5 : 3;
    const int i0 = blockIdx.x * 128;
    const int rmax = min(128, EP - i0);
    const int w = tid >> 6, lane = tid & 63;
    const int wr = w >> 1, wc = w & 1;
    const int lr = lane & 15;
    const int erow0 = (mos ? 0 : M2) + ty * EP + i0;
    const int w1base = mos ? 10 + ty * 5 : 26 + ty * 3;
    const int w2img = mos ? 20 + ty : 35 + ty;
    const int w3img = mos ? 22 + ty : 38 + ty;
    const int w4img = mos ? 24 + ty : 41 + ty;
    const float* b1 = mos ? mb1 : rb1;
    const float* b2 = mos ? mb2 : rb2;
    const float* b3 = mos ? mb3 : rb3;
    const float* b4 = mos ? mb4 : rb4;

    // ---- prologue: selfW1 image + e1s planes (single global read of e1s) ----
    stageWimg(wimg + (size_t)44 * 8192, WHL, tid);
    stageX_rows(e1s + (size_t)erow0 * 128, rmax, XH, XL, tid);
    if (tid < 64) sNW[tid] = nf1W[tid];
    else if (tid < 128) sNB[tid - 64] = nf1b[tid - 64];
    else if (tid < 192) sb[0][tid - 128] = b1[ty * 64 + tid - 128];
    __syncthreads();

    f32x4 acc[2][2], accS[2][2], ef2r[2][2];
    zacc(accS);
    mf_gemm64(XH, XL, WHL, WHL + 4096, accS, wr, wc, lane);   // self L1 (parked in regs)
    __syncthreads();                                          // all waves done reading WHL
    stageWimg(wimg + (size_t)w1base * 8192, WHL, tid);        // ef2 W1 channel 0
    __syncthreads();
    zacc(acc);
    mf_gemm64(XH, XL, WHL, WHL + 4096, acc, wr, wc, lane);    // ef2 L1 c0 (same planes)
    // ---- ef2 L1 channels 1..nch-1 ----
    for (int c = 1; c < nch; ++c) {
        __syncthreads();
        stageWimg(wimg + (size_t)(w1base + c) * 8192, WHL, tid);
        if (c == 1) stageX_pick(src_t, src_n, erow0, rmax, volt, nfo, sNW, sNB, XH, XL, tid);
        else if (c == 2) stageX_pick(dst_t, dst_n, erow0, rmax, volt, nfo, sNW, sNB, XH, XL, tid);
        else if (c == 3) stageX_pick(vg_t, vg_i, erow0, rmax, volt, nfo, sNW, sNB, XH, XL, tid);
        else stageX_pick(vb_t, vb_i, erow0, rmax, volt, nfo, sNW, sNB, XH, XL, tid);
        __syncthreads();
        mf_gemm64(XH, XL, WHL, WHL + 4096, acc, wr, wc, lane);
    }
    // ---- ef2 L2..L4 ----
    __syncthreads();
    writeback<true, true>(acc, sb[0], XH, XL, wr, wc, lane);  // gelu(+b1)
    stageWimg(wimg + (size_t)w2img * 8192, WHL, tid);
    if (tid < 64) sb[1][tid] = b2[ty * 64 + tid];
    __syncthreads();
    zacc(acc); mf_gemm64(XH, XL, WHL, WHL + 4096, acc, wr, wc, lane);
    __syncthreads();
    writeback<true, true>(acc, sb[1], XH, XL, wr, wc, lane);
    stageWimg(wimg + (size_t)w3img * 8192, WHL, tid);
    if (tid < 64) sb[2][tid] = b3[ty * 64 + tid];
    __syncthreads();
    zacc(acc); mf_gemm64(XH, XL, WHL, WHL + 4096, acc, wr, wc, lane);
    __syncthreads();
    writeback<true, true>(acc, sb[2], XH, XL, wr, wc, lane);
    stageWimg(wimg + (size_t)w4img * 8192, WHL, tid);
    if (tid < 64) sb[0][tid] = b4[ty * 64 + tid];
    else if (tid < 128) sb[1][tid - 64] = selb1[tid - 64];
    __syncthreads();
    zacc(acc); mf_gemm64(XH, XL, WHL, WHL + 4096, acc, wr, wc, lane);   // ef2 L4
    // ef2 result (with bias b4) held in registers
#pragma unroll
    for (int rt = 0; rt < 2; ++rt)
#pragma unroll
        for (int t = 0; t < 2; ++t)
#pragma unroll
            for (int r = 0; r < 4; ++r)
                ef2r[rt][t][r] = acc[rt][t][r] + sb[0][(wc * 2 + t) * 16 + lr];
    __syncthreads();   // all waves done reading planes/WHL
    // ---- self L2..L4: accS -> planes (gelu+selb1), then chain ----
    writeback<true, true>(accS, sb[1], XH, XL, wr, wc, lane);
    stageWimg(wimg + (size_t)45 * 8192, WHL, tid);
    if (tid < 64) sb[2][tid] = selb2[tid];
    __syncthreads();
    zacc(acc); mf_gemm64(XH, XL, WHL, WHL + 4096, acc, wr, wc, lane);
    __syncthreads();
    writeback<true, true>(acc, sb[2], XH, XL, wr, wc, lane);
    stageWimg(wimg + (size_t)46 * 8192, WHL, tid);
    if (tid < 64) sb[0][tid] = selb3[tid];
    __syncthreads();
    zacc(acc); mf_gemm64(XH, XL, WHL, WHL + 4096, acc, wr, wc, lane);
    __syncthreads();
    writeback<true, true>(acc, sb[0], XH, XL, wr, wc, lane);
    stageWimg(wimg + (size_t)47 * 8192, WHL, tid);
    if (tid < 64) sb[1][tid] = selb4[tid];
    __syncthreads();
    zacc(acc); mf_gemm64(XH, XL, WHL, WHL + 4096, acc, wr, wc, lane);   // self L4
    __syncthreads();
    // z = selfL4 + selb4 + ef2r -> planes (no gelu); stage score weights
    {
        int g = lane >> 4;
#pragma unroll
        for (int rt = 0; rt < 2; ++rt)
#pragma unroll
            for (int t = 0; t < 2; ++t)
#pragma unroll
                for (int r = 0; r < 4; ++r) {
                    int row = wr * 32 + rt * 16 + g * 4 + r;
                    int col = (wc * 2 + t) * 16 + lr;
                    float v = acc[rt][t][r] + sb[1][col] + ef2r[rt][t][r];
                    unsigned short h, l;
                    split2f(v, h, l);
                    int id = xidx(row, col);
                    XH[id] = h; XL[id] = l;
                }
    }
    stageWimg(wimg + (size_t)48 * 8192, WHL, tid);
    if (tid < 64) sb[2][tid] = scb[tid];
    __syncthreads();
    zacc(acc); mf_gemm64(XH, XL, WHL, WHL + 4096, acc, wr, wc, lane);   // score
    writeglob(acc, sb[2], out + (size_t)erow0 * 64, rmax, wr, wc, lane);
}

extern "C" void kernel_launch(void* const* d_in, const int* in_sizes, int n_in,
                              void* d_out, int out_size, void* d_ws, size_t ws_size,
                              hipStream_t stream) {
    const float* volt = (const float*)d_in[0];
    const float* dp   = (const float*)d_in[1];
    const int* src_t  = (const int*)d_in[2];
    const int* dst_t  = (const int*)d_in[3];
    const int* src_n  = (const int*)d_in[4];
    const int* dst_n  = (const int*)d_in[5];
    const int* vg_t   = (const int*)d_in[6];
    const int* vg_i   = (const int*)d_in[7];
    const int* vb_t   = (const int*)d_in[8];
    const int* vb_i   = (const int*)d_in[9];
    const float* nf1W = (const float*)d_in[11];
    const float* nf1b = (const float*)d_in[12];
    const float* e1W1 = (const float*)d_in[13];
    const float* e1b1 = (const float*)d_in[14];
    const float* e1W2 = (const float*)d_in[15];
    const float* e1b2 = (const float*)d_in[16];
    const float* e1W3 = (const float*)d_in[17];
    const float* e1b3 = (const float*)d_in[18];
    const float* mW1 = (const float*)d_in[19];  const float* mb1 = (const float*)d_in[20];
    const float* mW2 = (const float*)d_in[21];  const float* mb2 = (const float*)d_in[22];
    const float* mW3 = (const float*)d_in[23];  const float* mb3 = (const float*)d_in[24];
    const float* mW4 = (const float*)d_in[25];  const float* mb4 = (const float*)d_in[26];
    const float* rW1 = (const float*)d_in[27];  const float* rb1 = (const float*)d_in[28];
    const float* rW2 = (const float*)d_in[29];  const float* rb2 = (const float*)d_in[30];
    const float* rW3 = (const float*)d_in[31];  const float* rb3 = (const float*)d_in[32];
    const float* rW4 = (const float*)d_in[33];  const float* rb4 = (const float*)d_in[34];
    const float* selW1 = (const float*)d_in[35]; const float* selb1 = (const float*)d_in[36];
    const float* selW2 = (const float*)d_in[37]; const float* selb2 = (const float*)d_in[38];
    const float* selW3 = (const float*)d_in[39]; const float* selb3 = (const float*)d_in[40];
    const float* selW4 = (const float*)d_in[41]; const float* selb4 = (const float*)d_in[42];
    const float* scW = (const float*)d_in[43];   const float* scb = (const float*)d_in[44];

    // ws layout: NFO | WIMG | G | ints ; E1S table lives in d_out
    unsigned short* NFO  = (unsigned short*)d_ws;
    unsigned short* WIMG = NFO + (size_t)NOUT * 128;
    float* G = (float*)(WIMG + (size_t)NIMG * 8192);
    int* hist      = (int*)(G + 4096);
    int* cursor    = hist + NOUT;
    int* row_start = cursor + NOUT;
    int* elist     = row_start + NOUT + 1;
    unsigned short* E1S = (unsigned short*)d_out;

    const int T128_EP = (EP + 127) / 128;   // 469
    dim3 b256(256), b512(512);

    k_prepw<<<NIMG, b256, 0, stream>>>(e1W2, e1W3, mW1, mW2, mW3, mW4,
                                       rW1, rW2, rW3, rW4, selW1, selW2, selW3, selW4, scW, WIMG);
    {
        int nz = 4096 + NOUT + NOUT;   // G + hist + cursor
        k_zero<<<(nz + 255) / 256, b256, 0, stream>>>((int*)G, nz);
    }
    k_ef1<<<dim3(T128_EP, 5), b512, 0, stream>>>(dp, e1W1, e1b1, e1b2, e1b3, WIMG, E1S);
    k_hist<<<(NE + 255) / 256, b256, 0, stream>>>(dst_t, dst_n, hist);
    k_scan<<<1, 1024, 0, stream>>>(hist, row_start);
    k_scatter<<<(NE + 255) / 256, b256, 0, stream>>>(dst_t, dst_n, row_start, cursor, elist);
    k_gram<<<640, b256, 0, stream>>>(E1S, G);
    k_att<<<NOUT / 4, b256, 0, stream>>>(E1S, G, row_start, elist, NFO);
    k_fuse<<<dim3(T128_EP, 5), b512, 0, stream>>>(E1S, NFO, WIMG, volt,
        src_t, src_n, dst_t, dst_n, vg_t, vg_i, vb_t, vb_i, nf1W, nf1b,
        mb1, mb2, mb3, mb4, rb1, rb2, rb3, rb4,
        selb1, selb2, selb3, selb4, scb, (float*)d_out);
}

// Round 13
// 414.132 us; speedup vs baseline: 1.1850x; 1.1850x over previous
//
#include <hip/hip_runtime.h>
#include <hip/hip_bf16.h>

#define EP 60000
#define NE 300000
#define M2 120000
#define NIN 50000
#define NOUT 50000
#define PAD 65
#define NIMG 49
#define GP 72   // padded row-stride (u16) for transposed gram tiles; keeps b128 cols 16B-aligned

typedef __bf16 b16x8 __attribute__((ext_vector_type(8)));
typedef float f32x4 __attribute__((ext_vector_type(4)));
typedef unsigned short us8 __attribute__((ext_vector_type(8)));
typedef unsigned short us4 __attribute__((ext_vector_type(4)));

// exact-erf GELU — used in k_ef1 (feeds the Gram/softmax path; keep exact)
__device__ __forceinline__ float gelu_f(float x) {
    return 0.5f * x * (1.0f + erff(x * 0.70710678118654752440f));
}

// fast erf-GELU (A&S 7.1.26, |eps_erf|<=1.5e-7) — SAFE ONLY outside the Gram path
__device__ __forceinline__ float gelu_fast(float x) {
    float ax = fabsf(x) * 0.70710678118654752440f;
    float t = __builtin_amdgcn_rcpf(fmaf(0.3275911f, ax, 1.0f));
    float y = fmaf(fmaf(fmaf(fmaf(1.061405429f, t, -1.453152027f), t, 1.421413741f),
                        t, -0.284496736f), t, 0.254829592f) * t;
    float e = __expf(-ax * ax);
    float erf = fmaf(-y, e, 1.0f);
    return 0.5f * x * (1.0f + copysignf(erf, x));
}

__device__ __forceinline__ unsigned short bfhi(float f) {
    unsigned int u = __float_as_uint(f);
    u += 0x7FFFu + ((u >> 16) & 1u);   // RNE
    return (unsigned short)(u >> 16);
}

// RNE split (reconstruct err 2^-18) — used where the Gram path consumes the result
__device__ __forceinline__ void split2(float f, unsigned short& h, unsigned short& l) {
    h = bfhi(f);
    float fh = __uint_as_float(((unsigned int)h) << 16);
    l = bfhi(f - fh);
}

// fast truncating split (reconstruct err 2^-17, unbiased residual) — k_fuse interior
__device__ __forceinline__ void split2f(float f, unsigned short& h, unsigned short& l) {
    unsigned int u = __float_as_uint(f);
    h = (unsigned short)(u >> 16);
    float fh = __uint_as_float(u & 0xFFFF0000u);
    l = bfhi(f - fh);
}

__device__ __forceinline__ float bf2f(unsigned short u) {
    return __uint_as_float(((unsigned int)u) << 16);
}

// swizzled ushort-index into a [row][64] bf16 plane (XOR-swizzle, 8-ushort cells)
__device__ __forceinline__ int xidx(int row, int col) {
    return (row * 64 + col) ^ ((row & 7) << 3);
}

__device__ __forceinline__ b16x8 ldfrag(const unsigned short* p, int id) {
    return __builtin_bit_cast(b16x8, *(const us8*)(p + id));
}

__device__ __forceinline__ f32x4 MF(b16x8 a, b16x8 b, f32x4 c) {
    return __builtin_amdgcn_mfma_f32_16x16x32_bf16(a, b, c, 0, 0, 0);
}

__device__ __forceinline__ void zacc(f32x4 a[2][2]) {
#pragma unroll
    for (int i = 0; i < 2; ++i)
#pragma unroll
        for (int j = 0; j < 2; ++j) a[i][j] = (f32x4){0.f, 0.f, 0.f, 0.f};
}

__device__ __forceinline__ void gll16(const unsigned short* g, unsigned short* l) {
    __builtin_amdgcn_global_load_lds((const __attribute__((address_space(1))) void*)g,
                                     (__attribute__((address_space(3))) void*)l, 16, 0, 0);
}

// stage a prepped 16KB weight image via async global->LDS (512 threads: 2 issues each)
// RACE NOTE (R7/R8 lesson): stageWimg must be drained by __syncthreads() BEFORE any
// wave reads WHL; the pipelined ping-pong variant raced (NaN). Keep this pattern.
__device__ __forceinline__ void stageWimg(const unsigned short* __restrict__ img,
                                          unsigned short* __restrict__ WHL, int tid) {
    int w = tid >> 6, lane = tid & 63;
#pragma unroll
    for (int j = 0; j < 2; ++j)
        gll16(img + w * 1024 + j * 512 + lane * 8, WHL + w * 1024 + j * 512);
}

// stage 128 contiguous pre-split rows [row][hi0..63|lo0..63] -> swizzled planes (512 thr)
__device__ __forceinline__ void stageX_rows(const unsigned short* __restrict__ src, int rmax,
                                            unsigned short* __restrict__ XH, unsigned short* __restrict__ XL,
                                            int tid) {
#pragma unroll
    for (int q = 0; q < 4; ++q) {
        int f = q * 512 + tid;
        int row = f >> 4, cc = f & 15;
        int rc = min(row, rmax - 1);
        us8 v = *(const us8*)(src + (size_t)rc * 128 + cc * 8);
        unsigned short* pl = (cc < 8) ? XH : XL;
        *(us8*)(pl + xidx(row, (cc & 7) * 8)) = v;
    }
}

// stage pick rows: type==0 -> compute volt[idx]*nf1W+nf1b on the fly (4B read),
//                  type==1 -> gather pre-split NFO row (256B)
__device__ __forceinline__ void stageX_pick(const int* __restrict__ tp, const int* __restrict__ ix, int base,
                                            int rmax, const float* __restrict__ volt,
                                            const unsigned short* __restrict__ nfo,
                                            const float* __restrict__ sNW, const float* __restrict__ sNB,
                                            unsigned short* __restrict__ XH, unsigned short* __restrict__ XL,
                                            int tid) {
#pragma unroll
    for (int q = 0; q < 4; ++q) {
        int f = q * 512 + tid;
        int row = f >> 4, cc = f & 15;
        int rc = min(row, rmax - 1);
        int ty = tp[base + rc];
        int idx = ix[base + rc];
        int c8 = (cc & 7) * 8;
        unsigned short* pl = (cc < 8) ? XH : XL;
        us8 v;
        if (ty == 0) {
            float vv = volt[idx];
#pragma unroll
            for (int j = 0; j < 8; ++j) {
                float x = fmaf(vv, sNW[c8 + j], sNB[c8 + j]);
                unsigned short h, l;
                split2f(x, h, l);
                v[j] = (cc < 8) ? h : l;
            }
        } else {
            v = *(const us8*)(nfo + (size_t)idx * 128 + cc * 8);
        }
        *(us8*)(pl + xidx(row, c8)) = v;
    }
}

// 8-wave col-split gemm: wave (wr,wc) computes rows [wr*32,+32) x cols [wc*32,+32)
__device__ __forceinline__ void mf_gemm64(const unsigned short* __restrict__ XH, const unsigned short* __restrict__ XL,
                                          const unsigned short* __restrict__ WH, const unsigned short* __restrict__ WL,
                                          f32x4 acc[2][2], int wr, int wc, int lane) {
    int lr = lane & 15, g = lane >> 4;
#pragma unroll
    for (int kk = 0; kk < 2; ++kk) {
        int k0 = kk * 32 + g * 8;
        b16x8 ah[2], al[2];
#pragma unroll
        for (int rt = 0; rt < 2; ++rt) {
            int id = xidx(wr * 32 + rt * 16 + lr, k0);
            ah[rt] = ldfrag(XH, id);
            al[rt] = ldfrag(XL, id);
        }
#pragma unroll
        for (int t = 0; t < 2; ++t) {
            int id = xidx((wc * 2 + t) * 16 + lr, k0);
            b16x8 bh = ldfrag(WH, id), bl = ldfrag(WL, id);
#pragma unroll
            for (int rt = 0; rt < 2; ++rt) {
                acc[rt][t] = MF(ah[rt], bh, acc[rt][t]);
                acc[rt][t] = MF(ah[rt], bl, acc[rt][t]);
                acc[rt][t] = MF(al[rt], bh, acc[rt][t]);
            }
        }
    }
}

// acc + bias (+gelu) -> X planes (MUST be barrier-protected: waves share rows)
template <bool GELU, bool FAST>
__device__ __forceinline__ void writeback(f32x4 acc[2][2], const float* __restrict__ sb,
                                          unsigned short* __restrict__ XH, unsigned short* __restrict__ XL,
                                          int wr, int wc, int lane) {
    int lr = lane & 15, g = lane >> 4;
#pragma unroll
    for (int rt = 0; rt < 2; ++rt)
#pragma unroll
        for (int t = 0; t < 2; ++t)
#pragma unroll
            for (int r = 0; r < 4; ++r) {
                int row = wr * 32 + rt * 16 + g * 4 + r;
                int col = (wc * 2 + t) * 16 + lr;
                float v = acc[rt][t][r] + sb[col];
                if (GELU) v = FAST ? gelu_fast(v) : gelu_f(v);
                unsigned short h, l;
                if (FAST) split2f(v, h, l); else split2(v, h, l);
                int id = xidx(row, col);
                XH[id] = h; XL[id] = l;
            }
}

// plain cached stores (NT stores regressed WRITE_SIZE +77MB in R11 — do not reintroduce)
__device__ __forceinline__ void writeglob(f32x4 acc[2][2], const float* __restrict__ sb,
                                          float* __restrict__ dst, int rmax, int wr, int wc, int lane) {
    int lr = lane & 15, g = lane >> 4;
#pragma unroll
    for (int rt = 0; rt < 2; ++rt)
#pragma unroll
        for (int t = 0; t < 2; ++t)
#pragma unroll
            for (int r = 0; r < 4; ++r) {
                int row = wr * 32 + rt * 16 + g * 4 + r;
                if (row < rmax) {
                    int col = (wc * 2 + t) * 16 + lr;
                    dst[(size_t)row * 64 + col] = acc[rt][t][r] + sb[col];
                }
            }
}

// acc + bias -> split bf16 table rows [row][hi|lo] (RNE: feeds Gram path)
__device__ __forceinline__ void writeglob_split(f32x4 acc[2][2], const float* __restrict__ sb,
                                                unsigned short* __restrict__ dst, int rmax,
                                                int wr, int wc, int lane) {
    int lr = lane & 15, g = lane >> 4;
#pragma unroll
    for (int rt = 0; rt < 2; ++rt)
#pragma unroll
        for (int t = 0; t < 2; ++t)
#pragma unroll
            for (int r = 0; r < 4; ++r) {
                int row = wr * 32 + rt * 16 + g * 4 + r;
                if (row < rmax) {
                    int col = (wc * 2 + t) * 16 + lr;
                    float v = acc[rt][t][r] + sb[col];
                    unsigned short h, l;
                    split2(v, h, l);
                    dst[(size_t)row * 128 + col] = h;
                    dst[(size_t)row * 128 + 64 + col] = l;
                }
            }
}

__global__ void k_zero(int* __restrict__ p, int n) {
    int i = blockIdx.x * 256 + threadIdx.x;
    if (i < n) p[i] = 0;
}

// ---------------- prep: split+transpose+swizzle all 49 weight mats ----------------
__global__ __launch_bounds__(256) void k_prepw(
    const float* __restrict__ e1W2, const float* __restrict__ e1W3,
    const float* __restrict__ mW1, const float* __restrict__ mW2,
    const float* __restrict__ mW3, const float* __restrict__ mW4,
    const float* __restrict__ rW1, const float* __restrict__ rW2,
    const float* __restrict__ rW3, const float* __restrict__ rW4,
    const float* __restrict__ sw1, const float* __restrict__ sw2,
    const float* __restrict__ sw3, const float* __restrict__ sw4,
    const float* __restrict__ scw, unsigned short* __restrict__ wimg) {
    int b = blockIdx.x, tid = threadIdx.x;
    const float* src;
    if (b < 5) src = e1W2 + b * 4096;
    else if (b < 10) src = e1W3 + (b - 5) * 4096;
    else if (b < 20) src = mW1 + (b - 10) * 4096;
    else if (b < 22) src = mW2 + (b - 20) * 4096;
    else if (b < 24) src = mW3 + (b - 22) * 4096;
    else if (b < 26) src = mW4 + (b - 24) * 4096;
    else if (b < 35) src = rW1 + (b - 26) * 4096;
    else if (b < 38) src = rW2 + (b - 35) * 4096;
    else if (b < 41) src = rW3 + (b - 38) * 4096;
    else if (b < 44) src = rW4 + (b - 41) * 4096;
    else if (b == 44) src = sw1;
    else if (b == 45) src = sw2;
    else if (b == 46) src = sw3;
    else if (b == 47) src = sw4;
    else src = scw;
    unsigned short* dst = wimg + (size_t)b * 8192;
#pragma unroll
    for (int q = 0; q < 4; ++q) {
        int flat = q * 256 + tid;
        int k = flat >> 4, n4 = (flat & 15) * 4;
        float4 v = ((const float4*)src)[flat];
        float vv[4] = {v.x, v.y, v.z, v.w};
#pragma unroll
        for (int i = 0; i < 4; ++i) {
            unsigned short h, l;
            split2(vv[i], h, l);
            int id = xidx(n4 + i, k);
            dst[id] = h;
            dst[4096 + id] = l;
        }
    }
}

// ---------------- ef1: per-type 3-layer MLP -> split table (8-wave) ----------------
// Feeds Gram/softmax: exact gelu + RNE splits throughout.
__global__ __launch_bounds__(512, 4) void k_ef1(
    const float* __restrict__ dp,
    const float* __restrict__ w1, const float* __restrict__ b1,
    const float* __restrict__ b2, const float* __restrict__ b3,
    const unsigned short* __restrict__ wimg,
    unsigned short* __restrict__ e1s) {
    __shared__ unsigned short XH[8192], XL[8192], WHL[8192];
    __shared__ float sb[2][64], sW1[64], sB1[64];
    const int tid = threadIdx.x, ty = blockIdx.y;
    const int i0 = blockIdx.x * 128;
    const int rmax = min(128, EP - i0);
    const int w = tid >> 6, lane = tid & 63;
    const int wr = w >> 1, wc = w & 1;
    const size_t row0 = (size_t)ty * EP + i0;

    stageWimg(wimg + (size_t)ty * 8192, WHL, tid);
    if (tid < 64) { sW1[tid] = w1[ty * 64 + tid]; sB1[tid] = b1[ty * 64 + tid]; }
    else if (tid < 128) sb[0][tid - 64] = b2[ty * 64 + tid - 64];
    else if (tid < 192) sb[1][tid - 128] = b3[ty * 64 + tid - 128];
    __syncthreads();
    // L1: gelu(d*w1+b1) straight into planes
#pragma unroll
    for (int q = 0; q < 4; ++q) {
        int flat = q * 512 + tid;
        int rr = flat >> 4, cc = flat & 15;
        int rc = min(rr, rmax - 1);
        float d = dp[(size_t)ty * EP + i0 + rc];
        us4 h, l;
#pragma unroll
        for (int j = 0; j < 4; ++j) {
            int c = cc * 4 + j;
            float v = gelu_f(fmaf(d, sW1[c], sB1[c]));
            unsigned short hh, ll;
            split2(v, hh, ll);
            h[j] = hh; l[j] = ll;
        }
        *(us4*)(XH + xidx(rr, cc * 4)) = h;
        *(us4*)(XL + xidx(rr, cc * 4)) = l;
    }
    __syncthreads();
    f32x4 acc[2][2];
    zacc(acc); mf_gemm64(XH, XL, WHL, WHL + 4096, acc, wr, wc, lane);
    __syncthreads();
    writeback<true, false>(acc, sb[0], XH, XL, wr, wc, lane);
    stageWimg(wimg + (size_t)(5 + ty) * 8192, WHL, tid);
    __syncthreads();
    zacc(acc); mf_gemm64(XH, XL, WHL, WHL + 4096, acc, wr, wc, lane);
    writeglob_split(acc, sb[1], e1s + row0 * 128, rmax, wr, wc, lane);
}

// ---------------- f32 VALU helpers (attention path) ----------------
__device__ __forceinline__ void zero16(float* a) {
#pragma unroll
    for (int q = 0; q < 16; ++q) a[q] = 0.f;
}

__device__ __forceinline__ void stage4k(const float* __restrict__ g, float* __restrict__ l) {
    const float4* g4 = (const float4*)g;
    float4* l4 = (float4*)l;
    int t = threadIdx.x;
#pragma unroll
    for (int q = 0; q < 4; ++q) l4[q * 256 + t] = g4[q * 256 + t];
}

__device__ __forceinline__ void tile_gemm(const float* __restrict__ xt, const float* __restrict__ Wl,
                                          float* __restrict__ acc, int r, int c4) {
    const float4* W4 = (const float4*)Wl;
#pragma unroll 8
    for (int k = 0; k < 64; ++k) {
        float xv = xt[r * PAD + k];
#pragma unroll
        for (int q = 0; q < 4; ++q) {
            float4 w = W4[k * 16 + c4 + q];
            acc[q * 4 + 0] = fmaf(xv, w.x, acc[q * 4 + 0]);
            acc[q * 4 + 1] = fmaf(xv, w.y, acc[q * 4 + 1]);
            acc[q * 4 + 2] = fmaf(xv, w.z, acc[q * 4 + 2]);
            acc[q * 4 + 3] = fmaf(xv, w.w, acc[q * 4 + 3]);
        }
    }
}

// ---------------- G = ef1^T @ ef1 (MFMA, 3-term hi/lo split) ----------------
// Numerics: dropped lo*lo term ~5e-4 abs on O(1e3) G entries; f32 MFMA accumulator
// matches the old VALU f32 chain. Safe for the softmax (gaps >> perturbation).
__global__ __launch_bounds__(256) void k_gram(const unsigned short* __restrict__ e1s, float* __restrict__ G) {
    __shared__ unsigned short TH[64 * GP], TL[64 * GP];
    const int tid = threadIdx.x;
    const int wv = tid >> 6, lane = tid & 63;
    const int lr = lane & 15, g = lane >> 4;
    f32x4 acc[4];
#pragma unroll
    for (int t = 0; t < 4; ++t) acc[t] = (f32x4){0.f, 0.f, 0.f, 0.f};
    const int nchk = (NE + 63) >> 6;
    for (int ch = blockIdx.x; ch < nchk; ch += gridDim.x) {
        int r0 = ch * 64;
        __syncthreads();   // previous iteration's readers done
        // stage 64 rows transposed: TH/TL[col][row], zero-pad past NE
#pragma unroll
        for (int q = 0; q < 4; ++q) {
            int f = q * 256 + tid;
            int pl = f >> 9, rem = f & 511;
            int row = rem >> 3, cc = rem & 7;
            int rr = r0 + row;
            us8 v = (us8){0, 0, 0, 0, 0, 0, 0, 0};
            if (rr < NE) v = *(const us8*)(e1s + (size_t)rr * 128 + pl * 64 + cc * 8);
            unsigned short* dstp = pl ? TL : TH;
#pragma unroll
            for (int j = 0; j < 8; ++j) dstp[(cc * 8 + j) * GP + row] = v[j];
        }
        __syncthreads();
        // wave wv owns output row-tile a=wv; loop col-tiles b=0..3; k = edge rows
#pragma unroll
        for (int kk = 0; kk < 2; ++kk) {
            int k0 = kk * 32 + g * 8;
            b16x8 ah = ldfrag(TH, (wv * 16 + lr) * GP + k0);
            b16x8 al = ldfrag(TL, (wv * 16 + lr) * GP + k0);
#pragma unroll
            for (int b = 0; b < 4; ++b) {
                b16x8 bh = ldfrag(TH, (b * 16 + lr) * GP + k0);
                b16x8 bl = ldfrag(TL, (b * 16 + lr) * GP + k0);
                acc[b] = MF(ah, bh, acc[b]);
                acc[b] = MF(ah, bl, acc[b]);
                acc[b] = MF(al, bh, acc[b]);
            }
        }
    }
#pragma unroll
    for (int b = 0; b < 4; ++b)
#pragma unroll
        for (int r = 0; r < 4; ++r) {
            int row = wv * 16 + g * 4 + r;
            int col = b * 16 + lr;
            atomicAdd(&G[row * 64 + col], acc[b][r]);
        }
}

// ---------------- CSR build ----------------
__global__ void k_hist(const int* __restrict__ dst_t, const int* __restrict__ dst_n, int* __restrict__ hist) {
    int e = blockIdx.x * 256 + threadIdx.x;
    if (e < NE && dst_t[e] == 1) atomicAdd(&hist[dst_n[e]], 1);
}

__global__ __launch_bounds__(1024) void k_scan(const int* __restrict__ hist, int* __restrict__ row_start) {
    __shared__ int part[1024];
    const int tid = threadIdx.x;
    const int chunk = (NOUT + 1023) / 1024;
    int lo = tid * chunk, hi = min(lo + chunk, NOUT);
    int s = 0;
    for (int i = lo; i < hi; ++i) s += hist[i];
    part[tid] = s;
    __syncthreads();
    for (int off = 1; off < 1024; off <<= 1) {
        int v = part[tid];
        int add = (tid >= off) ? part[tid - off] : 0;
        __syncthreads();
        part[tid] = v + add;
        __syncthreads();
    }
    int base = (tid == 0) ? 0 : part[tid - 1];
    for (int i = lo; i < hi; ++i) { row_start[i] = base; base += hist[i]; }
    if (lo < NOUT && hi == NOUT) row_start[NOUT] = base;
}

__global__ void k_scatter(const int* __restrict__ dst_t, const int* __restrict__ dst_n,
                          const int* __restrict__ row_start, int* __restrict__ cursor, int* __restrict__ elist) {
    int e = blockIdx.x * 256 + threadIdx.x;
    if (e < NE && dst_t[e] == 1) {
        int n = dst_n[e];
        int pos = atomicAdd(&cursor[n], 1);
        elist[row_start[n] + pos] = e;
    }
}

// ---------------- logits for VALID edges only, CSR-compacted output ----------------
__global__ __launch_bounds__(256) void k_logits_c(const unsigned short* __restrict__ e1s,
                                                  const float* __restrict__ G,
                                                  const int* __restrict__ row_start,
                                                  const int* __restrict__ elist,
                                                  float* __restrict__ lgc) {
    __shared__ float A[64 * PAD], Wb[4096];
    const int tid = threadIdx.x;
    const int NV = row_start[NOUT];
    const int i0 = blockIdx.x * 64;
    if (i0 >= NV) return;
    const int rmax = min(64, NV - i0);
    const int r = tid & 63, c0 = (tid >> 6) * 16, c4 = c0 >> 2;
    stage4k(G, Wb);
#pragma unroll
    for (int q = 0; q < 4; ++q) {
        int flat = q * 256 + tid;
        int rr = flat >> 4, cc = flat & 15;
        int rc = min(rr, rmax - 1);
        int eid = elist[i0 + rc];
        const unsigned short* rp = e1s + (size_t)eid * 128;
        us4 h = *(const us4*)(rp + cc * 4);
        us4 l = *(const us4*)(rp + 64 + cc * 4);
        float* d = &A[rr * PAD + cc * 4];
#pragma unroll
        for (int j = 0; j < 4; ++j) d[j] = bf2f(h[j]) + bf2f(l[j]);
    }
    __syncthreads();
    float acc[16];
    zero16(acc); tile_gemm(A, Wb, acc, r, c4);
    if (r < rmax) {
        float* dst = lgc + (size_t)(i0 + r) * 64;
#pragma unroll
        for (int q = 0; q < 4; ++q)
            ((float4*)dst)[c4 + q] =
                make_float4(acc[q * 4 + 0], acc[q * 4 + 1], acc[q * 4 + 2], acc[q * 4 + 3]);
    }
}

// ---------------- segment softmax + weighted sum (single-pass online) ----------------
__global__ __launch_bounds__(256) void k_att(const float* __restrict__ lgc, const unsigned short* __restrict__ e1s,
                                             const int* __restrict__ row_start, const int* __restrict__ elist,
                                             unsigned short* __restrict__ nfo) {
    int n = blockIdx.x * 4 + (threadIdx.x >> 6);
    int lane = threadIdx.x & 63;
    if (n >= NOUT) return;
    int s = row_start[n], t = row_start[n + 1];
    float m = -3.0e38f, den = 0.f, num = 0.f;
    for (int i = s; i < t; ++i) {
        int eid = elist[i];
        float x = lgc[(size_t)i * 64 + lane];
        float e = bf2f(e1s[(size_t)eid * 128 + lane]) + bf2f(e1s[(size_t)eid * 128 + 64 + lane]);
        float mn = fmaxf(m, x);
        float sc = __expf(m - mn);
        float ex = __expf(x - mn);
        den = fmaf(den, sc, ex);
        num = fmaf(num, sc, ex * e);
        m = mn;
    }
    float v = (t > s) ? num / den : 0.f;
    unsigned short h, l;
    split2(v, h, l);
    nfo[(size_t)n * 128 + lane] = h;
    nfo[(size_t)n * 128 + 64 + lane] = l;
}

// ---------------- fused: self-L1 front-loaded + ef2 chain + self chain + score -> out ----------------
// Conservative barrier discipline (R6-verified). e1s read ONCE (prologue); self-L1 (accS)
// runs on those planes before the ef2 channel loop overwrites them. FAST numerics
// (approx gelu, truncating split) are safe here: this kernel is outside the Gram path.
__global__ __launch_bounds__(512, 4) void k_fuse(
    const unsigned short* __restrict__ e1s, const unsigned short* __restrict__ nfo,
    const unsigned short* __restrict__ wimg, const float* __restrict__ volt,
    const int* __restrict__ src_t, const int* __restrict__ src_n,
    const int* __restrict__ dst_t, const int* __restrict__ dst_n,
    const int* __restrict__ vg_t, const int* __restrict__ vg_i,
    const int* __restrict__ vb_t, const int* __restrict__ vb_i,
    const float* __restrict__ nf1W, const float* __restrict__ nf1b,
    const float* __restrict__ mb1, const float* __restrict__ mb2,
    const float* __restrict__ mb3, const float* __restrict__ mb4,
    const float* __restrict__ rb1, const float* __restrict__ rb2,
    const float* __restrict__ rb3, const float* __restrict__ rb4,
    const float* __restrict__ selb1, const float* __restrict__ selb2,
    const float* __restrict__ selb3, const float* __restrict__ selb4,
    const float* __restrict__ scb, float* __restrict__ out) {
    __shared__ unsigned short XH[8192], XL[8192], WHL[8192];
    __shared__ float sb[3][64], sNW[64], sNB[64];
    const int tid = threadIdx.x;
    const int gy = blockIdx.y;
    const bool mos = gy < 2;
    const int ty = mos ? gy : gy - 2;
    const int nch = mos ? 5 : 3;
    const int i0 = blockIdx.x * 128;
    const int rmax = min(128, EP - i0);
    const int w = tid >> 6, lane = tid & 63;
    const int wr = w >> 1, wc = w & 1;
    const int lr = lane & 15;
    const int erow0 = (mos ? 0 : M2) + ty * EP + i0;
    const int w1base = mos ? 10 + ty * 5 : 26 + ty * 3;
    const int w2img = mos ? 20 + ty : 35 + ty;
    const int w3img = mos ? 22 + ty : 38 + ty;
    const int w4img = mos ? 24 + ty : 41 + ty;
    const float* b1 = mos ? mb1 : rb1;
    const float* b2 = mos ? mb2 : rb2;
    const float* b3 = mos ? mb3 : rb3;
    const float* b4 = mos ? mb4 : rb4;

    // ---- prologue: selfW1 image + e1s planes (single global read of e1s) ----
    stageWimg(wimg + (size_t)44 * 8192, WHL, tid);
    stageX_rows(e1s + (size_t)erow0 * 128, rmax, XH, XL, tid);
    if (tid < 64) sNW[tid] = nf1W[tid];
    else if (tid < 128) sNB[tid - 64] = nf1b[tid - 64];
    else if (tid < 192) sb[0][tid - 128] = b1[ty * 64 + tid - 128];
    __syncthreads();

    f32x4 acc[2][2], accS[2][2], ef2r[2][2];
    zacc(accS);
    mf_gemm64(XH, XL, WHL, WHL + 4096, accS, wr, wc, lane);   // self L1 (parked in regs)
    __syncthreads();                                          // all waves done reading WHL
    stageWimg(wimg + (size_t)w1base * 8192, WHL, tid);        // ef2 W1 channel 0
    __syncthreads();
    zacc(acc);
    mf_gemm64(XH, XL, WHL, WHL + 4096, acc, wr, wc, lane);    // ef2 L1 c0 (same planes)
    // ---- ef2 L1 channels 1..nch-1 ----
    for (int c = 1; c < nch; ++c) {
        __syncthreads();
        stageWimg(wimg + (size_t)(w1base + c) * 8192, WHL, tid);
        if (c == 1) stageX_pick(src_t, src_n, erow0, rmax, volt, nfo, sNW, sNB, XH, XL, tid);
        else if (c == 2) stageX_pick(dst_t, dst_n, erow0, rmax, volt, nfo, sNW, sNB, XH, XL, tid);
        else if (c == 3) stageX_pick(vg_t, vg_i, erow0, rmax, volt, nfo, sNW, sNB, XH, XL, tid);
        else stageX_pick(vb_t, vb_i, erow0, rmax, volt, nfo, sNW, sNB, XH, XL, tid);
        __syncthreads();
        mf_gemm64(XH, XL, WHL, WHL + 4096, acc, wr, wc, lane);
    }
    // ---- ef2 L2..L4 ----
    __syncthreads();
    writeback<true, true>(acc, sb[0], XH, XL, wr, wc, lane);  // gelu(+b1)
    stageWimg(wimg + (size_t)w2img * 8192, WHL, tid);
    if (tid < 64) sb[1][tid] = b2[ty * 64 + tid];
    __syncthreads();
    zacc(acc); mf_gemm64(XH, XL, WHL, WHL + 4096, acc, wr, wc, lane);
    __syncthreads();
    writeback<true, true>(acc, sb[1], XH, XL, wr, wc, lane);
    stageWimg(wimg + (size_t)w3img * 8192, WHL, tid);
    if (tid < 64) sb[2][tid] = b3[ty * 64 + tid];
    __syncthreads();
    zacc(acc); mf_gemm64(XH, XL, WHL, WHL + 4096, acc, wr, wc, lane);
    __syncthreads();
    writeback<true, true>(acc, sb[2], XH, XL, wr, wc, lane);
    stageWimg(wimg + (size_t)w4img * 8192, WHL, tid);
    if (tid < 64) sb[0][tid] = b4[ty * 64 + tid];
    else if (tid < 128) sb[1][tid - 64] = selb1[tid - 64];
    __syncthreads();
    zacc(acc); mf_gemm64(XH, XL, WHL, WHL + 4096, acc, wr, wc, lane);   // ef2 L4
    // ef2 result (with bias b4) held in registers
#pragma unroll
    for (int rt = 0; rt < 2; ++rt)
#pragma unroll
        for (int t = 0; t < 2; ++t)
#pragma unroll
            for (int r = 0; r < 4; ++r)
                ef2r[rt][t][r] = acc[rt][t][r] + sb[0][(wc * 2 + t) * 16 + lr];
    __syncthreads();   // all waves done reading planes/WHL
    // ---- self L2..L4: accS -> planes (gelu+selb1), then chain ----
    writeback<true, true>(accS, sb[1], XH, XL, wr, wc, lane);
    stageWimg(wimg + (size_t)45 * 8192, WHL, tid);
    if (tid < 64) sb[2][tid] = selb2[tid];
    __syncthreads();
    zacc(acc); mf_gemm64(XH, XL, WHL, WHL + 4096, acc, wr, wc, lane);
    __syncthreads();
    writeback<true, true>(acc, sb[2], XH, XL, wr, wc, lane);
    stageWimg(wimg + (size_t)46 * 8192, WHL, tid);
    if (tid < 64) sb[0][tid] = selb3[tid];
    __syncthreads();
    zacc(acc); mf_gemm64(XH, XL, WHL, WHL + 4096, acc, wr, wc, lane);
    __syncthreads();
    writeback<true, true>(acc, sb[0], XH, XL, wr, wc, lane);
    stageWimg(wimg + (size_t)47 * 8192, WHL, tid);
    if (tid < 64) sb[1][tid] = selb4[tid];
    __syncthreads();
    zacc(acc); mf_gemm64(XH, XL, WHL, WHL + 4096, acc, wr, wc, lane);   // self L4
    __syncthreads();
    // z = selfL4 + selb4 + ef2r -> planes (no gelu); stage score weights
    {
        int g = lane >> 4;
#pragma unroll
        for (int rt = 0; rt < 2; ++rt)
#pragma unroll
            for (int t = 0; t < 2; ++t)
#pragma unroll
                for (int r = 0; r < 4; ++r) {
                    int row = wr * 32 + rt * 16 + g * 4 + r;
                    int col = (wc * 2 + t) * 16 + lr;
                    float v = acc[rt][t][r] + sb[1][col] + ef2r[rt][t][r];
                    unsigned short h, l;
                    split2f(v, h, l);
                    int id = xidx(row, col);
                    XH[id] = h; XL[id] = l;
                }
    }
    stageWimg(wimg + (size_t)48 * 8192, WHL, tid);
    if (tid < 64) sb[2][tid] = scb[tid];
    __syncthreads();
    zacc(acc); mf_gemm64(XH, XL, WHL, WHL + 4096, acc, wr, wc, lane);   // score
    writeglob(acc, sb[2], out + (size_t)erow0 * 64, rmax, wr, wc, lane);
}

extern "C" void kernel_launch(void* const* d_in, const int* in_sizes, int n_in,
                              void* d_out, int out_size, void* d_ws, size_t ws_size,
                              hipStream_t stream) {
    const float* volt = (const float*)d_in[0];
    const float* dp   = (const float*)d_in[1];
    const int* src_t  = (const int*)d_in[2];
    const int* dst_t  = (const int*)d_in[3];
    const int* src_n  = (const int*)d_in[4];
    const int* dst_n  = (const int*)d_in[5];
    const int* vg_t   = (const int*)d_in[6];
    const int* vg_i   = (const int*)d_in[7];
    const int* vb_t   = (const int*)d_in[8];
    const int* vb_i   = (const int*)d_in[9];
    const float* nf1W = (const float*)d_in[11];
    const float* nf1b = (const float*)d_in[12];
    const float* e1W1 = (const float*)d_in[13];
    const float* e1b1 = (const float*)d_in[14];
    const float* e1W2 = (const float*)d_in[15];
    const float* e1b2 = (const float*)d_in[16];
    const float* e1W3 = (const float*)d_in[17];
    const float* e1b3 = (const float*)d_in[18];
    const float* mW1 = (const float*)d_in[19];  const float* mb1 = (const float*)d_in[20];
    const float* mW2 = (const float*)d_in[21];  const float* mb2 = (const float*)d_in[22];
    const float* mW3 = (const float*)d_in[23];  const float* mb3 = (const float*)d_in[24];
    const float* mW4 = (const float*)d_in[25];  const float* mb4 = (const float*)d_in[26];
    const float* rW1 = (const float*)d_in[27];  const float* rb1 = (const float*)d_in[28];
    const float* rW2 = (const float*)d_in[29];  const float* rb2 = (const float*)d_in[30];
    const float* rW3 = (const float*)d_in[31];  const float* rb3 = (const float*)d_in[32];
    const float* rW4 = (const float*)d_in[33];  const float* rb4 = (const float*)d_in[34];
    const float* selW1 = (const float*)d_in[35]; const float* selb1 = (const float*)d_in[36];
    const float* selW2 = (const float*)d_in[37]; const float* selb2 = (const float*)d_in[38];
    const float* selW3 = (const float*)d_in[39]; const float* selb3 = (const float*)d_in[40];
    const float* selW4 = (const float*)d_in[41]; const float* selb4 = (const float*)d_in[42];
    const float* scW = (const float*)d_in[43];   const float* scb = (const float*)d_in[44];

    // ws layout: lgc f32 | NFO | WIMG | G | ints ; E1S table lives in d_out
    float* lgc = (float*)d_ws;
    unsigned short* NFO  = (unsigned short*)(lgc + (size_t)NE * 64);
    unsigned short* WIMG = NFO + (size_t)NOUT * 128;
    float* G = (float*)(WIMG + (size_t)NIMG * 8192);
    int* hist      = (int*)(G + 4096);
    int* cursor    = hist + NOUT;
    int* row_start = cursor + NOUT;
    int* elist     = row_start + NOUT + 1;
    unsigned short* E1S = (unsigned short*)d_out;

    const int T128_EP = (EP + 127) / 128;   // 469
    const int TILES_E = (NE + 63) / 64;     // 4688
    dim3 b256(256), b512(512);

    k_prepw<<<NIMG, b256, 0, stream>>>(e1W2, e1W3, mW1, mW2, mW3, mW4,
                                       rW1, rW2, rW3, rW4, selW1, selW2, selW3, selW4, scW, WIMG);
    {
        int nz = 4096 + NOUT + NOUT;   // G + hist + cursor
        k_zero<<<(nz + 255) / 256, b256, 0, stream>>>((int*)G, nz);
    }
    k_ef1<<<dim3(T128_EP, 5), b512, 0, stream>>>(dp, e1W1, e1b1, e1b2, e1b3, WIMG, E1S);
    k_hist<<<(NE + 255) / 256, b256, 0, stream>>>(dst_t, dst_n, hist);
    k_scan<<<1, 1024, 0, stream>>>(hist, row_start);
    k_scatter<<<(NE + 255) / 256, b256, 0, stream>>>(dst_t, dst_n, row_start, cursor, elist);
    k_gram<<<640, b256, 0, stream>>>(E1S, G);
    k_logits_c<<<TILES_E, b256, 0, stream>>>(E1S, G, row_start, elist, lgc);
    k_att<<<NOUT / 4, b256, 0, stream>>>(lgc, E1S, row_start, elist, NFO);
    k_fuse<<<dim3(T128_EP, 5), b512, 0, stream>>>(E1S, NFO, WIMG, volt,
        src_t, src_n, dst_t, dst_n, vg_t, vg_i, vb_t, vb_i, nf1W, nf1b,
        mb1, mb2, mb3, mb4, rb1, rb2, rb3, rb4,
        selb1, selb2, selb3, selb4, scb, (float*)d_out);
}

// Round 14
// 412.246 us; speedup vs baseline: 1.1904x; 1.0046x over previous
//
#include <hip/hip_runtime.h>
#include <hip/hip_bf16.h>

#define EP 60000
#define NE 300000
#define M2 120000
#define NIN 50000
#define NOUT 50000
#define PAD 65
#define NIMG 49
#define GIMG_ID 49
#define GP 72   // padded row-stride (u16) for transposed gram tiles

typedef __bf16 b16x8 __attribute__((ext_vector_type(8)));
typedef float f32x4 __attribute__((ext_vector_type(4)));
typedef unsigned short us8 __attribute__((ext_vector_type(8)));
typedef unsigned short us4 __attribute__((ext_vector_type(4)));

// exact-erf GELU — used in k_ef1 (feeds the Gram/softmax path; keep exact)
__device__ __forceinline__ float gelu_f(float x) {
    return 0.5f * x * (1.0f + erff(x * 0.70710678118654752440f));
}

// fast erf-GELU (A&S 7.1.26, |eps_erf|<=1.5e-7) — SAFE ONLY outside the Gram path
__device__ __forceinline__ float gelu_fast(float x) {
    float ax = fabsf(x) * 0.70710678118654752440f;
    float t = __builtin_amdgcn_rcpf(fmaf(0.3275911f, ax, 1.0f));
    float y = fmaf(fmaf(fmaf(fmaf(1.061405429f, t, -1.453152027f), t, 1.421413741f),
                        t, -0.284496736f), t, 0.254829592f) * t;
    float e = __expf(-ax * ax);
    float erf = fmaf(-y, e, 1.0f);
    return 0.5f * x * (1.0f + copysignf(erf, x));
}

__device__ __forceinline__ unsigned short bfhi(float f) {
    unsigned int u = __float_as_uint(f);
    u += 0x7FFFu + ((u >> 16) & 1u);   // RNE
    return (unsigned short)(u >> 16);
}

// RNE split — kept for reference paths
__device__ __forceinline__ void split2(float f, unsigned short& h, unsigned short& l) {
    h = bfhi(f);
    float fh = __uint_as_float(((unsigned int)h) << 16);
    l = bfhi(f - fh);
}

// truncating split (reconstruct err 2^-17; fine wherever hi+lo is reconstructed)
__device__ __forceinline__ void split2f(float f, unsigned short& h, unsigned short& l) {
    unsigned int u = __float_as_uint(f);
    h = (unsigned short)(u >> 16);
    float fh = __uint_as_float(u & 0xFFFF0000u);
    l = bfhi(f - fh);
}

__device__ __forceinline__ float bf2f(unsigned short u) {
    return __uint_as_float(((unsigned int)u) << 16);
}

// swizzled ushort-index into a [row][64] bf16 plane (XOR-swizzle, 8-ushort cells)
__device__ __forceinline__ int xidx(int row, int col) {
    return (row * 64 + col) ^ ((row & 7) << 3);
}

__device__ __forceinline__ b16x8 ldfrag(const unsigned short* p, int id) {
    return __builtin_bit_cast(b16x8, *(const us8*)(p + id));
}

__device__ __forceinline__ f32x4 MF(b16x8 a, b16x8 b, f32x4 c) {
    return __builtin_amdgcn_mfma_f32_16x16x32_bf16(a, b, c, 0, 0, 0);
}

__device__ __forceinline__ void zacc(f32x4 a[2][2]) {
#pragma unroll
    for (int i = 0; i < 2; ++i)
#pragma unroll
        for (int j = 0; j < 2; ++j) a[i][j] = (f32x4){0.f, 0.f, 0.f, 0.f};
}

__device__ __forceinline__ void gll16(const unsigned short* g, unsigned short* l) {
    __builtin_amdgcn_global_load_lds((const __attribute__((address_space(1))) void*)g,
                                     (__attribute__((address_space(3))) void*)l, 16, 0, 0);
}

// stage a prepped 16KB weight image via async global->LDS (512 threads: 2 issues each)
// RACE NOTE (R7/R8 lesson): stageWimg must be drained by __syncthreads() BEFORE any
// wave reads WHL; the pipelined ping-pong variant raced (NaN). Keep this pattern.
__device__ __forceinline__ void stageWimg(const unsigned short* __restrict__ img,
                                          unsigned short* __restrict__ WHL, int tid) {
    int w = tid >> 6, lane = tid & 63;
#pragma unroll
    for (int j = 0; j < 2; ++j)
        gll16(img + w * 1024 + j * 512 + lane * 8, WHL + w * 1024 + j * 512);
}

// stage 128 contiguous pre-split rows [row][hi0..63|lo0..63] -> swizzled planes (512 thr)
__device__ __forceinline__ void stageX_rows(const unsigned short* __restrict__ src, int rmax,
                                            unsigned short* __restrict__ XH, unsigned short* __restrict__ XL,
                                            int tid) {
#pragma unroll
    for (int q = 0; q < 4; ++q) {
        int f = q * 512 + tid;
        int row = f >> 4, cc = f & 15;
        int rc = min(row, rmax - 1);
        us8 v = *(const us8*)(src + (size_t)rc * 128 + cc * 8);
        unsigned short* pl = (cc < 8) ? XH : XL;
        *(us8*)(pl + xidx(row, (cc & 7) * 8)) = v;
    }
}

// stage 128 elist-indexed pre-split rows -> swizzled planes (512 thr; no decode)
__device__ __forceinline__ void stageX_elist(const unsigned short* __restrict__ e1s,
                                             const int* __restrict__ elist, int base, int rmax,
                                             unsigned short* __restrict__ XH, unsigned short* __restrict__ XL,
                                             int tid) {
#pragma unroll
    for (int q = 0; q < 4; ++q) {
        int f = q * 512 + tid;
        int row = f >> 4, cc = f & 15;
        int rc = min(row, rmax - 1);
        int eid = elist[base + rc];
        us8 v = *(const us8*)(e1s + (size_t)eid * 128 + cc * 8);
        unsigned short* pl = (cc < 8) ? XH : XL;
        *(us8*)(pl + xidx(row, (cc & 7) * 8)) = v;
    }
}

// stage pick rows: type==0 -> compute volt[idx]*nf1W+nf1b on the fly (4B read),
//                  type==1 -> gather pre-split NFO row (256B)
__device__ __forceinline__ void stageX_pick(const int* __restrict__ tp, const int* __restrict__ ix, int base,
                                            int rmax, const float* __restrict__ volt,
                                            const unsigned short* __restrict__ nfo,
                                            const float* __restrict__ sNW, const float* __restrict__ sNB,
                                            unsigned short* __restrict__ XH, unsigned short* __restrict__ XL,
                                            int tid) {
#pragma unroll
    for (int q = 0; q < 4; ++q) {
        int f = q * 512 + tid;
        int row = f >> 4, cc = f & 15;
        int rc = min(row, rmax - 1);
        int ty = tp[base + rc];
        int idx = ix[base + rc];
        int c8 = (cc & 7) * 8;
        unsigned short* pl = (cc < 8) ? XH : XL;
        us8 v;
        if (ty == 0) {
            float vv = volt[idx];
#pragma unroll
            for (int j = 0; j < 8; ++j) {
                float x = fmaf(vv, sNW[c8 + j], sNB[c8 + j]);
                unsigned short h, l;
                split2f(x, h, l);
                v[j] = (cc < 8) ? h : l;
            }
        } else {
            v = *(const us8*)(nfo + (size_t)idx * 128 + cc * 8);
        }
        *(us8*)(pl + xidx(row, c8)) = v;
    }
}

// 8-wave col-split gemm: wave (wr,wc) computes rows [wr*32,+32) x cols [wc*32,+32)
__device__ __forceinline__ void mf_gemm64(const unsigned short* __restrict__ XH, const unsigned short* __restrict__ XL,
                                          const unsigned short* __restrict__ WH, const unsigned short* __restrict__ WL,
                                          f32x4 acc[2][2], int wr, int wc, int lane) {
    int lr = lane & 15, g = lane >> 4;
#pragma unroll
    for (int kk = 0; kk < 2; ++kk) {
        int k0 = kk * 32 + g * 8;
        b16x8 ah[2], al[2];
#pragma unroll
        for (int rt = 0; rt < 2; ++rt) {
            int id = xidx(wr * 32 + rt * 16 + lr, k0);
            ah[rt] = ldfrag(XH, id);
            al[rt] = ldfrag(XL, id);
        }
#pragma unroll
        for (int t = 0; t < 2; ++t) {
            int id = xidx((wc * 2 + t) * 16 + lr, k0);
            b16x8 bh = ldfrag(WH, id), bl = ldfrag(WL, id);
#pragma unroll
            for (int rt = 0; rt < 2; ++rt) {
                acc[rt][t] = MF(ah[rt], bh, acc[rt][t]);
                acc[rt][t] = MF(ah[rt], bl, acc[rt][t]);
                acc[rt][t] = MF(al[rt], bh, acc[rt][t]);
            }
        }
    }
}

// acc + bias (+gelu) -> X planes (MUST be barrier-protected: waves share rows)
template <bool GELU, bool FAST>
__device__ __forceinline__ void writeback(f32x4 acc[2][2], const float* __restrict__ sb,
                                          unsigned short* __restrict__ XH, unsigned short* __restrict__ XL,
                                          int wr, int wc, int lane) {
    int lr = lane & 15, g = lane >> 4;
#pragma unroll
    for (int rt = 0; rt < 2; ++rt)
#pragma unroll
        for (int t = 0; t < 2; ++t)
#pragma unroll
            for (int r = 0; r < 4; ++r) {
                int row = wr * 32 + rt * 16 + g * 4 + r;
                int col = (wc * 2 + t) * 16 + lr;
                float v = acc[rt][t][r] + sb[col];
                if (GELU) v = FAST ? gelu_fast(v) : gelu_f(v);
                unsigned short h, l;
                if (FAST) split2f(v, h, l); else split2(v, h, l);
                int id = xidx(row, col);
                XH[id] = h; XL[id] = l;
            }
}

// plain cached stores (NT stores regressed WRITE_SIZE +77MB in R11 — do not reintroduce)
__device__ __forceinline__ void writeglob(f32x4 acc[2][2], const float* __restrict__ sb,
                                          float* __restrict__ dst, int rmax, int wr, int wc, int lane) {
    int lr = lane & 15, g = lane >> 4;
#pragma unroll
    for (int rt = 0; rt < 2; ++rt)
#pragma unroll
        for (int t = 0; t < 2; ++t)
#pragma unroll
            for (int r = 0; r < 4; ++r) {
                int row = wr * 32 + rt * 16 + g * 4 + r;
                if (row < rmax) {
                    int col = (wc * 2 + t) * 16 + lr;
                    dst[(size_t)row * 64 + col] = acc[rt][t][r] + sb[col];
                }
            }
}

// no-bias variant (logits)
__device__ __forceinline__ void writeglob_nb(f32x4 acc[2][2], float* __restrict__ dst,
                                             int rmax, int wr, int wc, int lane) {
    int lr = lane & 15, g = lane >> 4;
#pragma unroll
    for (int rt = 0; rt < 2; ++rt)
#pragma unroll
        for (int t = 0; t < 2; ++t)
#pragma unroll
            for (int r = 0; r < 4; ++r) {
                int row = wr * 32 + rt * 16 + g * 4 + r;
                if (row < rmax) {
                    int col = (wc * 2 + t) * 16 + lr;
                    dst[(size_t)row * 64 + col] = acc[rt][t][r];
                }
            }
}

// acc + bias -> split bf16 table rows [row][hi|lo] (reconstruction-consumed: trunc split ok)
__device__ __forceinline__ void writeglob_split(f32x4 acc[2][2], const float* __restrict__ sb,
                                                unsigned short* __restrict__ dst, int rmax,
                                                int wr, int wc, int lane) {
    int lr = lane & 15, g = lane >> 4;
#pragma unroll
    for (int rt = 0; rt < 2; ++rt)
#pragma unroll
        for (int t = 0; t < 2; ++t)
#pragma unroll
            for (int r = 0; r < 4; ++r) {
                int row = wr * 32 + rt * 16 + g * 4 + r;
                if (row < rmax) {
                    int col = (wc * 2 + t) * 16 + lr;
                    float v = acc[rt][t][r] + sb[col];
                    unsigned short h, l;
                    split2f(v, h, l);
                    dst[(size_t)row * 128 + col] = h;
                    dst[(size_t)row * 128 + 64 + col] = l;
                }
            }
}

__global__ void k_zero(int* __restrict__ p, int n) {
    int i = blockIdx.x * 256 + threadIdx.x;
    if (i < n) p[i] = 0;
}

// ---------------- prep: split+transpose+swizzle all 49 weight mats ----------------
__global__ __launch_bounds__(256) void k_prepw(
    const float* __restrict__ e1W2, const float* __restrict__ e1W3,
    const float* __restrict__ mW1, const float* __restrict__ mW2,
    const float* __restrict__ mW3, const float* __restrict__ mW4,
    const float* __restrict__ rW1, const float* __restrict__ rW2,
    const float* __restrict__ rW3, const float* __restrict__ rW4,
    const float* __restrict__ sw1, const float* __restrict__ sw2,
    const float* __restrict__ sw3, const float* __restrict__ sw4,
    const float* __restrict__ scw, unsigned short* __restrict__ wimg) {
    int b = blockIdx.x, tid = threadIdx.x;
    const float* src;
    if (b < 5) src = e1W2 + b * 4096;
    else if (b < 10) src = e1W3 + (b - 5) * 4096;
    else if (b < 20) src = mW1 + (b - 10) * 4096;
    else if (b < 22) src = mW2 + (b - 20) * 4096;
    else if (b < 24) src = mW3 + (b - 22) * 4096;
    else if (b < 26) src = mW4 + (b - 24) * 4096;
    else if (b < 35) src = rW1 + (b - 26) * 4096;
    else if (b < 38) src = rW2 + (b - 35) * 4096;
    else if (b < 41) src = rW3 + (b - 38) * 4096;
    else if (b < 44) src = rW4 + (b - 41) * 4096;
    else if (b == 44) src = sw1;
    else if (b == 45) src = sw2;
    else if (b == 46) src = sw3;
    else if (b == 47) src = sw4;
    else src = scw;
    unsigned short* dst = wimg + (size_t)b * 8192;
#pragma unroll
    for (int q = 0; q < 4; ++q) {
        int flat = q * 256 + tid;
        int k = flat >> 4, n4 = (flat & 15) * 4;
        float4 v = ((const float4*)src)[flat];
        float vv[4] = {v.x, v.y, v.z, v.w};
#pragma unroll
        for (int i = 0; i < 4; ++i) {
            unsigned short h, l;
            split2(vv[i], h, l);
            int id = xidx(n4 + i, k);
            dst[id] = h;
            dst[4096 + id] = l;
        }
    }
}

// ---------------- prep: split+transpose G (f32 64x64) into image slot 49 ----------------
__global__ __launch_bounds__(256) void k_prepg(const float* __restrict__ G,
                                               unsigned short* __restrict__ wimg) {
    int tid = threadIdx.x;
    unsigned short* dst = wimg + (size_t)GIMG_ID * 8192;
#pragma unroll
    for (int q = 0; q < 4; ++q) {
        int flat = q * 256 + tid;
        int k = flat >> 4, n4 = (flat & 15) * 4;
        float4 v = ((const float4*)G)[flat];
        float vv[4] = {v.x, v.y, v.z, v.w};
#pragma unroll
        for (int i = 0; i < 4; ++i) {
            unsigned short h, l;
            split2(vv[i], h, l);
            int id = xidx(n4 + i, k);
            dst[id] = h;
            dst[4096 + id] = l;
        }
    }
}

// ---------------- ef1: per-type 3-layer MLP -> split table (8-wave) ----------------
// Feeds Gram/softmax: exact gelu; splits are reconstruction-consumed (trunc ok).
__global__ __launch_bounds__(512, 4) void k_ef1(
    const float* __restrict__ dp,
    const float* __restrict__ w1, const float* __restrict__ b1,
    const float* __restrict__ b2, const float* __restrict__ b3,
    const unsigned short* __restrict__ wimg,
    unsigned short* __restrict__ e1s) {
    __shared__ unsigned short XH[8192], XL[8192], WHL[8192];
    __shared__ float sb[2][64], sW1[64], sB1[64];
    const int tid = threadIdx.x, ty = blockIdx.y;
    const int i0 = blockIdx.x * 128;
    const int rmax = min(128, EP - i0);
    const int w = tid >> 6, lane = tid & 63;
    const int wr = w >> 1, wc = w & 1;
    const size_t row0 = (size_t)ty * EP + i0;

    stageWimg(wimg + (size_t)ty * 8192, WHL, tid);
    if (tid < 64) { sW1[tid] = w1[ty * 64 + tid]; sB1[tid] = b1[ty * 64 + tid]; }
    else if (tid < 128) sb[0][tid - 64] = b2[ty * 64 + tid - 64];
    else if (tid < 192) sb[1][tid - 128] = b3[ty * 64 + tid - 128];
    __syncthreads();
    // L1: gelu(d*w1+b1) straight into planes
#pragma unroll
    for (int q = 0; q < 4; ++q) {
        int flat = q * 512 + tid;
        int rr = flat >> 4, cc = flat & 15;
        int rc = min(rr, rmax - 1);
        float d = dp[(size_t)ty * EP + i0 + rc];
        us4 h, l;
#pragma unroll
        for (int j = 0; j < 4; ++j) {
            int c = cc * 4 + j;
            float v = gelu_f(fmaf(d, sW1[c], sB1[c]));
            unsigned short hh, ll;
            split2f(v, hh, ll);
            h[j] = hh; l[j] = ll;
        }
        *(us4*)(XH + xidx(rr, cc * 4)) = h;
        *(us4*)(XL + xidx(rr, cc * 4)) = l;
    }
    __syncthreads();
    f32x4 acc[2][2];
    zacc(acc); mf_gemm64(XH, XL, WHL, WHL + 4096, acc, wr, wc, lane);
    __syncthreads();
    writeback<true, false>(acc, sb[0], XH, XL, wr, wc, lane);
    stageWimg(wimg + (size_t)(5 + ty) * 8192, WHL, tid);
    __syncthreads();
    zacc(acc); mf_gemm64(XH, XL, WHL, WHL + 4096, acc, wr, wc, lane);
    writeglob_split(acc, sb[1], e1s + row0 * 128, rmax, wr, wc, lane);
}

// ---------------- G = ef1^T @ ef1 (MFMA, 3-term hi/lo split) ----------------
__global__ __launch_bounds__(256) void k_gram(const unsigned short* __restrict__ e1s, float* __restrict__ G) {
    __shared__ unsigned short TH[64 * GP], TL[64 * GP];
    const int tid = threadIdx.x;
    const int wv = tid >> 6, lane = tid & 63;
    const int lr = lane & 15, g = lane >> 4;
    f32x4 acc[4];
#pragma unroll
    for (int t = 0; t < 4; ++t) acc[t] = (f32x4){0.f, 0.f, 0.f, 0.f};
    const int nchk = (NE + 63) >> 6;
    for (int ch = blockIdx.x; ch < nchk; ch += gridDim.x) {
        int r0 = ch * 64;
        __syncthreads();   // previous iteration's readers done
#pragma unroll
        for (int q = 0; q < 4; ++q) {
            int f = q * 256 + tid;
            int pl = f >> 9, rem = f & 511;
            int row = rem >> 3, cc = rem & 7;
            int rr = r0 + row;
            us8 v = (us8){0, 0, 0, 0, 0, 0, 0, 0};
            if (rr < NE) v = *(const us8*)(e1s + (size_t)rr * 128 + pl * 64 + cc * 8);
            unsigned short* dstp = pl ? TL : TH;
#pragma unroll
            for (int j = 0; j < 8; ++j) dstp[(cc * 8 + j) * GP + row] = v[j];
        }
        __syncthreads();
#pragma unroll
        for (int kk = 0; kk < 2; ++kk) {
            int k0 = kk * 32 + g * 8;
            b16x8 ah = ldfrag(TH, (wv * 16 + lr) * GP + k0);
            b16x8 al = ldfrag(TL, (wv * 16 + lr) * GP + k0);
#pragma unroll
            for (int b = 0; b < 4; ++b) {
                b16x8 bh = ldfrag(TH, (b * 16 + lr) * GP + k0);
                b16x8 bl = ldfrag(TL, (b * 16 + lr) * GP + k0);
                acc[b] = MF(ah, bh, acc[b]);
                acc[b] = MF(ah, bl, acc[b]);
                acc[b] = MF(al, bh, acc[b]);
            }
        }
    }
#pragma unroll
    for (int b = 0; b < 4; ++b)
#pragma unroll
        for (int r = 0; r < 4; ++r) {
            int row = wv * 16 + g * 4 + r;
            int col = b * 16 + lr;
            atomicAdd(&G[row * 64 + col], acc[b][r]);
        }
}

// ---------------- CSR build ----------------
__global__ void k_hist(const int* __restrict__ dst_t, const int* __restrict__ dst_n, int* __restrict__ hist) {
    int e = blockIdx.x * 256 + threadIdx.x;
    if (e < NE && dst_t[e] == 1) atomicAdd(&hist[dst_n[e]], 1);
}

__global__ __launch_bounds__(1024) void k_scan(const int* __restrict__ hist, int* __restrict__ row_start) {
    __shared__ int part[1024];
    const int tid = threadIdx.x;
    const int chunk = (NOUT + 1023) / 1024;
    int lo = tid * chunk, hi = min(lo + chunk, NOUT);
    int s = 0;
    for (int i = lo; i < hi; ++i) s += hist[i];
    part[tid] = s;
    __syncthreads();
    for (int off = 1; off < 1024; off <<= 1) {
        int v = part[tid];
        int add = (tid >= off) ? part[tid - off] : 0;
        __syncthreads();
        part[tid] = v + add;
        __syncthreads();
    }
    int base = (tid == 0) ? 0 : part[tid - 1];
    for (int i = lo; i < hi; ++i) { row_start[i] = base; base += hist[i]; }
    if (lo < NOUT && hi == NOUT) row_start[NOUT] = base;
}

__global__ void k_scatter(const int* __restrict__ dst_t, const int* __restrict__ dst_n,
                          const int* __restrict__ row_start, int* __restrict__ cursor, int* __restrict__ elist) {
    int e = blockIdx.x * 256 + threadIdx.x;
    if (e < NE && dst_t[e] == 1) {
        int n = dst_n[e];
        int pos = atomicAdd(&cursor[n], 1);
        elist[row_start[n] + pos] = e;
    }
}

// ---------------- logits for VALID edges (MFMA; A = e1s frags, B = G image) ----------------
__global__ __launch_bounds__(512, 4) void k_logits_c(const unsigned short* __restrict__ e1s,
                                                     const unsigned short* __restrict__ wimg,
                                                     const int* __restrict__ row_start,
                                                     const int* __restrict__ elist,
                                                     float* __restrict__ lgc) {
    __shared__ unsigned short XH[8192], XL[8192], WHL[8192];
    const int tid = threadIdx.x;
    const int NV = row_start[NOUT];
    const int i0 = blockIdx.x * 128;
    if (i0 >= NV) return;
    const int rmax = min(128, NV - i0);
    const int w = tid >> 6, lane = tid & 63;
    const int wr = w >> 1, wc = w & 1;

    stageWimg(wimg + (size_t)GIMG_ID * 8192, WHL, tid);
    stageX_elist(e1s, elist, i0, rmax, XH, XL, tid);
    __syncthreads();
    f32x4 acc[2][2];
    zacc(acc); mf_gemm64(XH, XL, WHL, WHL + 4096, acc, wr, wc, lane);
    writeglob_nb(acc, lgc + (size_t)i0 * 64, rmax, wr, wc, lane);
}

// ---------------- segment softmax + weighted sum (single-pass online) ----------------
__global__ __launch_bounds__(256) void k_att(const float* __restrict__ lgc, const unsigned short* __restrict__ e1s,
                                             const int* __restrict__ row_start, const int* __restrict__ elist,
                                             unsigned short* __restrict__ nfo) {
    int n = blockIdx.x * 4 + (threadIdx.x >> 6);
    int lane = threadIdx.x & 63;
    if (n >= NOUT) return;
    int s = row_start[n], t = row_start[n + 1];
    float m = -3.0e38f, den = 0.f, num = 0.f;
    for (int i = s; i < t; ++i) {
        int eid = elist[i];
        float x = lgc[(size_t)i * 64 + lane];
        float e = bf2f(e1s[(size_t)eid * 128 + lane]) + bf2f(e1s[(size_t)eid * 128 + 64 + lane]);
        float mn = fmaxf(m, x);
        float sc = __expf(m - mn);
        float ex = __expf(x - mn);
        den = fmaf(den, sc, ex);
        num = fmaf(num, sc, ex * e);
        m = mn;
    }
    float v = (t > s) ? num / den : 0.f;
    unsigned short h, l;
    split2f(v, h, l);
    nfo[(size_t)n * 128 + lane] = h;
    nfo[(size_t)n * 128 + 64 + lane] = l;
}

// ---------------- fused: self-L1 front-loaded + ef2 chain + self chain + score -> out ----------------
// Conservative barrier discipline (R6-verified). e1s read ONCE (prologue); self-L1 (accS)
// runs on those planes before the ef2 channel loop overwrites them. FAST numerics
// (approx gelu, truncating split) are safe here: this kernel is outside the Gram path.
__global__ __launch_bounds__(512, 4) void k_fuse(
    const unsigned short* __restrict__ e1s, const unsigned short* __restrict__ nfo,
    const unsigned short* __restrict__ wimg, const float* __restrict__ volt,
    const int* __restrict__ src_t, const int* __restrict__ src_n,
    const int* __restrict__ dst_t, const int* __restrict__ dst_n,
    const int* __restrict__ vg_t, const int* __restrict__ vg_i,
    const int* __restrict__ vb_t, const int* __restrict__ vb_i,
    const float* __restrict__ nf1W, const float* __restrict__ nf1b,
    const float* __restrict__ mb1, const float* __restrict__ mb2,
    const float* __restrict__ mb3, const float* __restrict__ mb4,
    const float* __restrict__ rb1, const float* __restrict__ rb2,
    const float* __restrict__ rb3, const float* __restrict__ rb4,
    const float* __restrict__ selb1, const float* __restrict__ selb2,
    const float* __restrict__ selb3, const float* __restrict__ selb4,
    const float* __restrict__ scb, float* __restrict__ out) {
    __shared__ unsigned short XH[8192], XL[8192], WHL[8192];
    __shared__ float sb[3][64], sNW[64], sNB[64];
    const int tid = threadIdx.x;
    const int gy = blockIdx.y;
    const bool mos = gy < 2;
    const int ty = mos ? gy : gy - 2;
    const int nch = mos ? 5 : 3;
    const int i0 = blockIdx.x * 128;
    const int rmax = min(128, EP - i0);
    const int w = tid >> 6, lane = tid & 63;
    const int wr = w >> 1, wc = w & 1;
    const int lr = lane & 15;
    const int erow0 = (mos ? 0 : M2) + ty * EP + i0;
    const int w1base = mos ? 10 + ty * 5 : 26 + ty * 3;
    const int w2img = mos ? 20 + ty : 35 + ty;
    const int w3img = mos ? 22 + ty : 38 + ty;
    const int w4img = mos ? 24 + ty : 41 + ty;
    const float* b1 = mos ? mb1 : rb1;
    const float* b2 = mos ? mb2 : rb2;
    const float* b3 = mos ? mb3 : rb3;
    const float* b4 = mos ? mb4 : rb4;

    // ---- prologue: selfW1 image + e1s planes (single global read of e1s) ----
    stageWimg(wimg + (size_t)44 * 8192, WHL, tid);
    stageX_rows(e1s + (size_t)erow0 * 128, rmax, XH, XL, tid);
    if (tid < 64) sNW[tid] = nf1W[tid];
    else if (tid < 128) sNB[tid - 64] = nf1b[tid - 64];
    else if (tid < 192) sb[0][tid - 128] = b1[ty * 64 + tid - 128];
    __syncthreads();

    f32x4 acc[2][2], accS[2][2], ef2r[2][2];
    zacc(accS);
    mf_gemm64(XH, XL, WHL, WHL + 4096, accS, wr, wc, lane);   // self L1 (parked in regs)
    __syncthreads();                                          // all waves done reading WHL
    stageWimg(wimg + (size_t)w1base * 8192, WHL, tid);        // ef2 W1 channel 0
    __syncthreads();
    zacc(acc);
    mf_gemm64(XH, XL, WHL, WHL + 4096, acc, wr, wc, lane);    // ef2 L1 c0 (same planes)
    // ---- ef2 L1 channels 1..nch-1 ----
    for (int c = 1; c < nch; ++c) {
        __syncthreads();
        stageWimg(wimg + (size_t)(w1base + c) * 8192, WHL, tid);
        if (c == 1) stageX_pick(src_t, src_n, erow0, rmax, volt, nfo, sNW, sNB, XH, XL, tid);
        else if (c == 2) stageX_pick(dst_t, dst_n, erow0, rmax, volt, nfo, sNW, sNB, XH, XL, tid);
        else if (c == 3) stageX_pick(vg_t, vg_i, erow0, rmax, volt, nfo, sNW, sNB, XH, XL, tid);
        else stageX_pick(vb_t, vb_i, erow0, rmax, volt, nfo, sNW, sNB, XH, XL, tid);
        __syncthreads();
        mf_gemm64(XH, XL, WHL, WHL + 4096, acc, wr, wc, lane);
    }
    // ---- ef2 L2..L4 ----
    __syncthreads();
    writeback<true, true>(acc, sb[0], XH, XL, wr, wc, lane);  // gelu(+b1)
    stageWimg(wimg + (size_t)w2img * 8192, WHL, tid);
    if (tid < 64) sb[1][tid] = b2[ty * 64 + tid];
    __syncthreads();
    zacc(acc); mf_gemm64(XH, XL, WHL, WHL + 4096, acc, wr, wc, lane);
    __syncthreads();
    writeback<true, true>(acc, sb[1], XH, XL, wr, wc, lane);
    stageWimg(wimg + (size_t)w3img * 8192, WHL, tid);
    if (tid < 64) sb[2][tid] = b3[ty * 64 + tid];
    __syncthreads();
    zacc(acc); mf_gemm64(XH, XL, WHL, WHL + 4096, acc, wr, wc, lane);
    __syncthreads();
    writeback<true, true>(acc, sb[2], XH, XL, wr, wc, lane);
    stageWimg(wimg + (size_t)w4img * 8192, WHL, tid);
    if (tid < 64) sb[0][tid] = b4[ty * 64 + tid];
    else if (tid < 128) sb[1][tid - 64] = selb1[tid - 64];
    __syncthreads();
    zacc(acc); mf_gemm64(XH, XL, WHL, WHL + 4096, acc, wr, wc, lane);   // ef2 L4
    // ef2 result (with bias b4) held in registers
#pragma unroll
    for (int rt = 0; rt < 2; ++rt)
#pragma unroll
        for (int t = 0; t < 2; ++t)
#pragma unroll
            for (int r = 0; r < 4; ++r)
                ef2r[rt][t][r] = acc[rt][t][r] + sb[0][(wc * 2 + t) * 16 + lr];
    __syncthreads();   // all waves done reading planes/WHL
    // ---- self L2..L4: accS -> planes (gelu+selb1), then chain ----
    writeback<true, true>(accS, sb[1], XH, XL, wr, wc, lane);
    stageWimg(wimg + (size_t)45 * 8192, WHL, tid);
    if (tid < 64) sb[2][tid] = selb2[tid];
    __syncthreads();
    zacc(acc); mf_gemm64(XH, XL, WHL, WHL + 4096, acc, wr, wc, lane);
    __syncthreads();
    writeback<true, true>(acc, sb[2], XH, XL, wr, wc, lane);
    stageWimg(wimg + (size_t)46 * 8192, WHL, tid);
    if (tid < 64) sb[0][tid] = selb3[tid];
    __syncthreads();
    zacc(acc); mf_gemm64(XH, XL, WHL, WHL + 4096, acc, wr, wc, lane);
    __syncthreads();
    writeback<true, true>(acc, sb[0], XH, XL, wr, wc, lane);
    stageWimg(wimg + (size_t)47 * 8192, WHL, tid);
    if (tid < 64) sb[1][tid] = selb4[tid];
    __syncthreads();
    zacc(acc); mf_gemm64(XH, XL, WHL, WHL + 4096, acc, wr, wc, lane);   // self L4
    __syncthreads();
    // z = selfL4 + selb4 + ef2r -> planes (no gelu); stage score weights
    {
        int g = lane >> 4;
#pragma unroll
        for (int rt = 0; rt < 2; ++rt)
#pragma unroll
            for (int t = 0; t < 2; ++t)
#pragma unroll
                for (int r = 0; r < 4; ++r) {
                    int row = wr * 32 + rt * 16 + g * 4 + r;
                    int col = (wc * 2 + t) * 16 + lr;
                    float v = acc[rt][t][r] + sb[1][col] + ef2r[rt][t][r];
                    unsigned short h, l;
                    split2f(v, h, l);
                    int id = xidx(row, col);
                    XH[id] = h; XL[id] = l;
                }
    }
    stageWimg(wimg + (size_t)48 * 8192, WHL, tid);
    if (tid < 64) sb[2][tid] = scb[tid];
    __syncthreads();
    zacc(acc); mf_gemm64(XH, XL, WHL, WHL + 4096, acc, wr, wc, lane);   // score
    writeglob(acc, sb[2], out + (size_t)erow0 * 64, rmax, wr, wc, lane);
}

extern "C" void kernel_launch(void* const* d_in, const int* in_sizes, int n_in,
                              void* d_out, int out_size, void* d_ws, size_t ws_size,
                              hipStream_t stream) {
    const float* volt = (const float*)d_in[0];
    const float* dp   = (const float*)d_in[1];
    const int* src_t  = (const int*)d_in[2];
    const int* dst_t  = (const int*)d_in[3];
    const int* src_n  = (const int*)d_in[4];
    const int* dst_n  = (const int*)d_in[5];
    const int* vg_t   = (const int*)d_in[6];
    const int* vg_i   = (const int*)d_in[7];
    const int* vb_t   = (const int*)d_in[8];
    const int* vb_i   = (const int*)d_in[9];
    const float* nf1W = (const float*)d_in[11];
    const float* nf1b = (const float*)d_in[12];
    const float* e1W1 = (const float*)d_in[13];
    const float* e1b1 = (const float*)d_in[14];
    const float* e1W2 = (const float*)d_in[15];
    const float* e1b2 = (const float*)d_in[16];
    const float* e1W3 = (const float*)d_in[17];
    const float* e1b3 = (const float*)d_in[18];
    const float* mW1 = (const float*)d_in[19];  const float* mb1 = (const float*)d_in[20];
    const float* mW2 = (const float*)d_in[21];  const float* mb2 = (const float*)d_in[22];
    const float* mW3 = (const float*)d_in[23];  const float* mb3 = (const float*)d_in[24];
    const float* mW4 = (const float*)d_in[25];  const float* mb4 = (const float*)d_in[26];
    const float* rW1 = (const float*)d_in[27];  const float* rb1 = (const float*)d_in[28];
    const float* rW2 = (const float*)d_in[29];  const float* rb2 = (const float*)d_in[30];
    const float* rW3 = (const float*)d_in[31];  const float* rb3 = (const float*)d_in[32];
    const float* rW4 = (const float*)d_in[33];  const float* rb4 = (const float*)d_in[34];
    const float* selW1 = (const float*)d_in[35]; const float* selb1 = (const float*)d_in[36];
    const float* selW2 = (const float*)d_in[37]; const float* selb2 = (const float*)d_in[38];
    const float* selW3 = (const float*)d_in[39]; const float* selb3 = (const float*)d_in[40];
    const float* selW4 = (const float*)d_in[41]; const float* selb4 = (const float*)d_in[42];
    const float* scW = (const float*)d_in[43];   const float* scb = (const float*)d_in[44];

    // ws layout: lgc f32 | NFO | WIMG(50) | G | ints ; E1S table lives in d_out
    float* lgc = (float*)d_ws;
    unsigned short* NFO  = (unsigned short*)(lgc + (size_t)NE * 64);
    unsigned short* WIMG = NFO + (size_t)NOUT * 128;
    float* G = (float*)(WIMG + (size_t)(NIMG + 1) * 8192);
    int* hist      = (int*)(G + 4096);
    int* cursor    = hist + NOUT;
    int* row_start = cursor + NOUT;
    int* elist     = row_start + NOUT + 1;
    unsigned short* E1S = (unsigned short*)d_out;

    const int T128_EP = (EP + 127) / 128;   // 469
    const int T128_E  = (NE + 127) / 128;   // 2344
    dim3 b256(256), b512(512);

    k_prepw<<<NIMG, b256, 0, stream>>>(e1W2, e1W3, mW1, mW2, mW3, mW4,
                                       rW1, rW2, rW3, rW4, selW1, selW2, selW3, selW4, scW, WIMG);
    {
        int nz = 4096 + NOUT + NOUT;   // G + hist + cursor
        k_zero<<<(nz + 255) / 256, b256, 0, stream>>>((int*)G, nz);
    }
    k_ef1<<<dim3(T128_EP, 5), b512, 0, stream>>>(dp, e1W1, e1b1, e1b2, e1b3, WIMG, E1S);
    k_hist<<<(NE + 255) / 256, b256, 0, stream>>>(dst_t, dst_n, hist);
    k_scan<<<1, 1024, 0, stream>>>(hist, row_start);
    k_scatter<<<(NE + 255) / 256, b256, 0, stream>>>(dst_t, dst_n, row_start, cursor, elist);
    k_gram<<<640, b256, 0, stream>>>(E1S, G);
    k_prepg<<<1, b256, 0, stream>>>(G, WIMG);
    k_logits_c<<<T128_E, b512, 0, stream>>>(E1S, WIMG, row_start, elist, lgc);
    k_att<<<NOUT / 4, b256, 0, stream>>>(lgc, E1S, row_start, elist, NFO);
    k_fuse<<<dim3(T128_EP, 5), b512, 0, stream>>>(E1S, NFO, WIMG, volt,
        src_t, src_n, dst_t, dst_n, vg_t, vg_i, vb_t, vb_i, nf1W, nf1b,
        mb1, mb2, mb3, mb4, rb1, rb2, rb3, rb4,
        selb1, selb2, selb3, selb4, scb, (float*)d_out);
}

// Round 15
// 402.665 us; speedup vs baseline: 1.2187x; 1.0238x over previous
//
#include <hip/hip_runtime.h>
#include <hip/hip_bf16.h>

#define EP 60000
#define NE 300000
#define M2 120000
#define NIN 50000
#define NOUT 50000
#define PAD 65
#define NIMG 49
#define GIMG_ID 49
#define GP 72   // padded row-stride (u16) for transposed gram tiles

typedef __bf16 b16x8 __attribute__((ext_vector_type(8)));
typedef float f32x4 __attribute__((ext_vector_type(4)));
typedef unsigned short us8 __attribute__((ext_vector_type(8)));
typedef unsigned short us4 __attribute__((ext_vector_type(4)));

// exact-erf GELU — used in k_ef1 (feeds the Gram/softmax path; keep exact)
__device__ __forceinline__ float gelu_f(float x) {
    return 0.5f * x * (1.0f + erff(x * 0.70710678118654752440f));
}

// fast erf-GELU (A&S 7.1.26, |eps_erf|<=1.5e-7) — SAFE ONLY outside the Gram path
__device__ __forceinline__ float gelu_fast(float x) {
    float ax = fabsf(x) * 0.70710678118654752440f;
    float t = __builtin_amdgcn_rcpf(fmaf(0.3275911f, ax, 1.0f));
    float y = fmaf(fmaf(fmaf(fmaf(1.061405429f, t, -1.453152027f), t, 1.421413741f),
                        t, -0.284496736f), t, 0.254829592f) * t;
    float e = __expf(-ax * ax);
    float erf = fmaf(-y, e, 1.0f);
    return 0.5f * x * (1.0f + copysignf(erf, x));
}

__device__ __forceinline__ unsigned short bfhi(float f) {
    unsigned int u = __float_as_uint(f);
    u += 0x7FFFu + ((u >> 16) & 1u);   // RNE
    return (unsigned short)(u >> 16);
}

// RNE split — weight images (Gram-path consumers exist)
__device__ __forceinline__ void split2(float f, unsigned short& h, unsigned short& l) {
    h = bfhi(f);
    float fh = __uint_as_float(((unsigned int)h) << 16);
    l = bfhi(f - fh);
}

// trunc-hi + RNE-lo split (reconstruct err +-2^-19, UNBIASED) — REQUIRED for anything
// feeding the Gram sum (e1s): a biased residual accumulates coherently over 300k
// products and corrupts logits O(0.1+) (R7 lesson).
__device__ __forceinline__ void split2f(float f, unsigned short& h, unsigned short& l) {
    unsigned int u = __float_as_uint(f);
    h = (unsigned short)(u >> 16);
    float fh = __uint_as_float(u & 0xFFFF0000u);
    l = bfhi(f - fh);
}

// full-trunc split (bias -2^-18|x|, cheapest) — k_fuse interior / NFO only (bounded
// non-accumulating consumers), NEVER for e1s/Gram.
__device__ __forceinline__ void split2t(float f, unsigned short& h, unsigned short& l) {
    unsigned int u = __float_as_uint(f);
    h = (unsigned short)(u >> 16);
    float fh = __uint_as_float(u & 0xFFFF0000u);
    float r = f - fh;
    l = (unsigned short)(__float_as_uint(r) >> 16);
}

__device__ __forceinline__ float bf2f(unsigned short u) {
    return __uint_as_float(((unsigned int)u) << 16);
}

// swizzled ushort-index into a [row][64] bf16 plane (XOR-swizzle, 8-ushort cells)
__device__ __forceinline__ int xidx(int row, int col) {
    return (row * 64 + col) ^ ((row & 7) << 3);
}

__device__ __forceinline__ b16x8 ldfrag(const unsigned short* p, int id) {
    return __builtin_bit_cast(b16x8, *(const us8*)(p + id));
}

__device__ __forceinline__ f32x4 MF(b16x8 a, b16x8 b, f32x4 c) {
    return __builtin_amdgcn_mfma_f32_16x16x32_bf16(a, b, c, 0, 0, 0);
}

__device__ __forceinline__ void zacc(f32x4 a[2][2]) {
#pragma unroll
    for (int i = 0; i < 2; ++i)
#pragma unroll
        for (int j = 0; j < 2; ++j) a[i][j] = (f32x4){0.f, 0.f, 0.f, 0.f};
}

__device__ __forceinline__ void gll16(const unsigned short* g, unsigned short* l) {
    __builtin_amdgcn_global_load_lds((const __attribute__((address_space(1))) void*)g,
                                     (__attribute__((address_space(3))) void*)l, 16, 0, 0);
}

// stage a prepped 16KB weight image via async global->LDS (512 threads: 2 issues each)
// RACE NOTE (R7/R8 lesson): stageWimg must be drained by __syncthreads() BEFORE any
// wave reads WHL; the pipelined ping-pong variant raced (NaN). Keep this pattern.
__device__ __forceinline__ void stageWimg(const unsigned short* __restrict__ img,
                                          unsigned short* __restrict__ WHL, int tid) {
    int w = tid >> 6, lane = tid & 63;
#pragma unroll
    for (int j = 0; j < 2; ++j)
        gll16(img + w * 1024 + j * 512 + lane * 8, WHL + w * 1024 + j * 512);
}

// stage 128 contiguous pre-split rows [row][hi0..63|lo0..63] -> swizzled planes (512 thr)
__device__ __forceinline__ void stageX_rows(const unsigned short* __restrict__ src, int rmax,
                                            unsigned short* __restrict__ XH, unsigned short* __restrict__ XL,
                                            int tid) {
#pragma unroll
    for (int q = 0; q < 4; ++q) {
        int f = q * 512 + tid;
        int row = f >> 4, cc = f & 15;
        int rc = min(row, rmax - 1);
        us8 v = *(const us8*)(src + (size_t)rc * 128 + cc * 8);
        unsigned short* pl = (cc < 8) ? XH : XL;
        *(us8*)(pl + xidx(row, (cc & 7) * 8)) = v;
    }
}

// stage 128 elist-indexed pre-split rows -> swizzled planes (512 thr; no decode)
__device__ __forceinline__ void stageX_elist(const unsigned short* __restrict__ e1s,
                                             const int* __restrict__ elist, int base, int rmax,
                                             unsigned short* __restrict__ XH, unsigned short* __restrict__ XL,
                                             int tid) {
#pragma unroll
    for (int q = 0; q < 4; ++q) {
        int f = q * 512 + tid;
        int row = f >> 4, cc = f & 15;
        int rc = min(row, rmax - 1);
        int eid = elist[base + rc];
        us8 v = *(const us8*)(e1s + (size_t)eid * 128 + cc * 8);
        unsigned short* pl = (cc < 8) ? XH : XL;
        *(us8*)(pl + xidx(row, (cc & 7) * 8)) = v;
    }
}

// stage pick rows: type==0 -> compute volt[idx]*nf1W+nf1b on the fly (4B read),
//                  type==1 -> gather pre-split NFO row (256B)
__device__ __forceinline__ void stageX_pick(const int* __restrict__ tp, const int* __restrict__ ix, int base,
                                            int rmax, const float* __restrict__ volt,
                                            const unsigned short* __restrict__ nfo,
                                            const float* __restrict__ sNW, const float* __restrict__ sNB,
                                            unsigned short* __restrict__ XH, unsigned short* __restrict__ XL,
                                            int tid) {
#pragma unroll
    for (int q = 0; q < 4; ++q) {
        int f = q * 512 + tid;
        int row = f >> 4, cc = f & 15;
        int rc = min(row, rmax - 1);
        int ty = tp[base + rc];
        int idx = ix[base + rc];
        int c8 = (cc & 7) * 8;
        unsigned short* pl = (cc < 8) ? XH : XL;
        us8 v;
        if (ty == 0) {
            float vv = volt[idx];
#pragma unroll
            for (int j = 0; j < 8; ++j) {
                float x = fmaf(vv, sNW[c8 + j], sNB[c8 + j]);
                unsigned short h, l;
                split2t(x, h, l);
                v[j] = (cc < 8) ? h : l;
            }
        } else {
            v = *(const us8*)(nfo + (size_t)idx * 128 + cc * 8);
        }
        *(us8*)(pl + xidx(row, c8)) = v;
    }
}

// 8-wave col-split gemm: wave (wr,wc) computes rows [wr*32,+32) x cols [wc*32,+32)
__device__ __forceinline__ void mf_gemm64(const unsigned short* __restrict__ XH, const unsigned short* __restrict__ XL,
                                          const unsigned short* __restrict__ WH, const unsigned short* __restrict__ WL,
                                          f32x4 acc[2][2], int wr, int wc, int lane) {
    int lr = lane & 15, g = lane >> 4;
#pragma unroll
    for (int kk = 0; kk < 2; ++kk) {
        int k0 = kk * 32 + g * 8;
        b16x8 ah[2], al[2];
#pragma unroll
        for (int rt = 0; rt < 2; ++rt) {
            int id = xidx(wr * 32 + rt * 16 + lr, k0);
            ah[rt] = ldfrag(XH, id);
            al[rt] = ldfrag(XL, id);
        }
#pragma unroll
        for (int t = 0; t < 2; ++t) {
            int id = xidx((wc * 2 + t) * 16 + lr, k0);
            b16x8 bh = ldfrag(WH, id), bl = ldfrag(WL, id);
#pragma unroll
            for (int rt = 0; rt < 2; ++rt) {
                acc[rt][t] = MF(ah[rt], bh, acc[rt][t]);
                acc[rt][t] = MF(ah[rt], bl, acc[rt][t]);
                acc[rt][t] = MF(al[rt], bh, acc[rt][t]);
            }
        }
    }
}

// acc + bias (+gelu) -> X planes (MUST be barrier-protected: waves share rows)
template <bool GELU, bool FAST>
__device__ __forceinline__ void writeback(f32x4 acc[2][2], const float* __restrict__ sb,
                                          unsigned short* __restrict__ XH, unsigned short* __restrict__ XL,
                                          int wr, int wc, int lane) {
    int lr = lane & 15, g = lane >> 4;
#pragma unroll
    for (int rt = 0; rt < 2; ++rt)
#pragma unroll
        for (int t = 0; t < 2; ++t)
#pragma unroll
            for (int r = 0; r < 4; ++r) {
                int row = wr * 32 + rt * 16 + g * 4 + r;
                int col = (wc * 2 + t) * 16 + lr;
                float v = acc[rt][t][r] + sb[col];
                if (GELU) v = FAST ? gelu_fast(v) : gelu_f(v);
                unsigned short h, l;
                if (FAST) split2t(v, h, l); else split2(v, h, l);
                int id = xidx(row, col);
                XH[id] = h; XL[id] = l;
            }
}

// plain cached stores (NT stores regressed WRITE_SIZE +77MB in R11 — do not reintroduce)
__device__ __forceinline__ void writeglob(f32x4 acc[2][2], const float* __restrict__ sb,
                                          float* __restrict__ dst, int rmax, int wr, int wc, int lane) {
    int lr = lane & 15, g = lane >> 4;
#pragma unroll
    for (int rt = 0; rt < 2; ++rt)
#pragma unroll
        for (int t = 0; t < 2; ++t)
#pragma unroll
            for (int r = 0; r < 4; ++r) {
                int row = wr * 32 + rt * 16 + g * 4 + r;
                if (row < rmax) {
                    int col = (wc * 2 + t) * 16 + lr;
                    dst[(size_t)row * 64 + col] = acc[rt][t][r] + sb[col];
                }
            }
}

// no-bias variant (logits)
__device__ __forceinline__ void writeglob_nb(f32x4 acc[2][2], float* __restrict__ dst,
                                             int rmax, int wr, int wc, int lane) {
    int lr = lane & 15, g = lane >> 4;
#pragma unroll
    for (int rt = 0; rt < 2; ++rt)
#pragma unroll
        for (int t = 0; t < 2; ++t)
#pragma unroll
            for (int r = 0; r < 4; ++r) {
                int row = wr * 32 + rt * 16 + g * 4 + r;
                if (row < rmax) {
                    int col = (wc * 2 + t) * 16 + lr;
                    dst[(size_t)row * 64 + col] = acc[rt][t][r];
                }
            }
}

// acc + bias -> split bf16 table rows [row][hi|lo]
// e1s feeds the GRAM SUM -> must stay unbiased: split2f (RNE residual), NOT split2t.
__device__ __forceinline__ void writeglob_split(f32x4 acc[2][2], const float* __restrict__ sb,
                                                unsigned short* __restrict__ dst, int rmax,
                                                int wr, int wc, int lane) {
    int lr = lane & 15, g = lane >> 4;
#pragma unroll
    for (int rt = 0; rt < 2; ++rt)
#pragma unroll
        for (int t = 0; t < 2; ++t)
#pragma unroll
            for (int r = 0; r < 4; ++r) {
                int row = wr * 32 + rt * 16 + g * 4 + r;
                if (row < rmax) {
                    int col = (wc * 2 + t) * 16 + lr;
                    float v = acc[rt][t][r] + sb[col];
                    unsigned short h, l;
                    split2f(v, h, l);
                    dst[(size_t)row * 128 + col] = h;
                    dst[(size_t)row * 128 + 64 + col] = l;
                }
            }
}

// ---------------- prep: split+transpose+swizzle all 49 weight mats; tail blocks zero ints ----------------
__global__ __launch_bounds__(256) void k_prepw(
    const float* __restrict__ e1W2, const float* __restrict__ e1W3,
    const float* __restrict__ mW1, const float* __restrict__ mW2,
    const float* __restrict__ mW3, const float* __restrict__ mW4,
    const float* __restrict__ rW1, const float* __restrict__ rW2,
    const float* __restrict__ rW3, const float* __restrict__ rW4,
    const float* __restrict__ sw1, const float* __restrict__ sw2,
    const float* __restrict__ sw3, const float* __restrict__ sw4,
    const float* __restrict__ scw, unsigned short* __restrict__ wimg,
    int* __restrict__ zbase, int nz) {
    int b = blockIdx.x, tid = threadIdx.x;
    if (b >= NIMG) {
        int i = (b - NIMG) * 256 + tid;
        if (i < nz) zbase[i] = 0;
        return;
    }
    const float* src;
    if (b < 5) src = e1W2 + b * 4096;
    else if (b < 10) src = e1W3 + (b - 5) * 4096;
    else if (b < 20) src = mW1 + (b - 10) * 4096;
    else if (b < 22) src = mW2 + (b - 20) * 4096;
    else if (b < 24) src = mW3 + (b - 22) * 4096;
    else if (b < 26) src = mW4 + (b - 24) * 4096;
    else if (b < 35) src = rW1 + (b - 26) * 4096;
    else if (b < 38) src = rW2 + (b - 35) * 4096;
    else if (b < 41) src = rW3 + (b - 38) * 4096;
    else if (b < 44) src = rW4 + (b - 41) * 4096;
    else if (b == 44) src = sw1;
    else if (b == 45) src = sw2;
    else if (b == 46) src = sw3;
    else if (b == 47) src = sw4;
    else src = scw;
    unsigned short* dst = wimg + (size_t)b * 8192;
#pragma unroll
    for (int q = 0; q < 4; ++q) {
        int flat = q * 256 + tid;
        int k = flat >> 4, n4 = (flat & 15) * 4;
        float4 v = ((const float4*)src)[flat];
        float vv[4] = {v.x, v.y, v.z, v.w};
#pragma unroll
        for (int i = 0; i < 4; ++i) {
            unsigned short h, l;
            split2(vv[i], h, l);
            int id = xidx(n4 + i, k);
            dst[id] = h;
            dst[4096 + id] = l;
        }
    }
}

// ---------------- prep: split+transpose G (f32 64x64) into image slot 49 ----------------
__global__ __launch_bounds__(256) void k_prepg(const float* __restrict__ G,
                                               unsigned short* __restrict__ wimg) {
    int tid = threadIdx.x;
    unsigned short* dst = wimg + (size_t)GIMG_ID * 8192;
#pragma unroll
    for (int q = 0; q < 4; ++q) {
        int flat = q * 256 + tid;
        int k = flat >> 4, n4 = (flat & 15) * 4;
        float4 v = ((const float4*)G)[flat];
        float vv[4] = {v.x, v.y, v.z, v.w};
#pragma unroll
        for (int i = 0; i < 4; ++i) {
            unsigned short h, l;
            split2(vv[i], h, l);
            int id = xidx(n4 + i, k);
            dst[id] = h;
            dst[4096 + id] = l;
        }
    }
}

// ---------------- ef1: per-type 3-layer MLP -> split table (8-wave) ----------------
// Feeds Gram/softmax: exact gelu; e1s splits unbiased (split2f).
__global__ __launch_bounds__(512, 4) void k_ef1(
    const float* __restrict__ dp,
    const float* __restrict__ w1, const float* __restrict__ b1,
    const float* __restrict__ b2, const float* __restrict__ b3,
    const unsigned short* __restrict__ wimg,
    unsigned short* __restrict__ e1s) {
    __shared__ unsigned short XH[8192], XL[8192], WHL[8192];
    __shared__ float sb[2][64], sW1[64], sB1[64];
    const int tid = threadIdx.x, ty = blockIdx.y;
    const int i0 = blockIdx.x * 128;
    const int rmax = min(128, EP - i0);
    const int w = tid >> 6, lane = tid & 63;
    const int wr = w >> 1, wc = w & 1;
    const size_t row0 = (size_t)ty * EP + i0;

    stageWimg(wimg + (size_t)ty * 8192, WHL, tid);
    if (tid < 64) { sW1[tid] = w1[ty * 64 + tid]; sB1[tid] = b1[ty * 64 + tid]; }
    else if (tid < 128) sb[0][tid - 64] = b2[ty * 64 + tid - 64];
    else if (tid < 192) sb[1][tid - 128] = b3[ty * 64 + tid - 128];
    __syncthreads();
    // L1: gelu(d*w1+b1) straight into planes
#pragma unroll
    for (int q = 0; q < 4; ++q) {
        int flat = q * 512 + tid;
        int rr = flat >> 4, cc = flat & 15;
        int rc = min(rr, rmax - 1);
        float d = dp[(size_t)ty * EP + i0 + rc];
        us4 h, l;
#pragma unroll
        for (int j = 0; j < 4; ++j) {
            int c = cc * 4 + j;
            float v = gelu_f(fmaf(d, sW1[c], sB1[c]));
            unsigned short hh, ll;
            split2f(v, hh, ll);
            h[j] = hh; l[j] = ll;
        }
        *(us4*)(XH + xidx(rr, cc * 4)) = h;
        *(us4*)(XL + xidx(rr, cc * 4)) = l;
    }
    __syncthreads();
    f32x4 acc[2][2];
    zacc(acc); mf_gemm64(XH, XL, WHL, WHL + 4096, acc, wr, wc, lane);
    __syncthreads();
    writeback<true, false>(acc, sb[0], XH, XL, wr, wc, lane);
    stageWimg(wimg + (size_t)(5 + ty) * 8192, WHL, tid);
    __syncthreads();
    zacc(acc); mf_gemm64(XH, XL, WHL, WHL + 4096, acc, wr, wc, lane);
    writeglob_split(acc, sb[1], e1s + row0 * 128, rmax, wr, wc, lane);
}

// ---------------- G = ef1^T @ ef1 (MFMA, 3-term hi/lo split) ----------------
__global__ __launch_bounds__(256) void k_gram(const unsigned short* __restrict__ e1s, float* __restrict__ G) {
    __shared__ unsigned short TH[64 * GP], TL[64 * GP];
    const int tid = threadIdx.x;
    const int wv = tid >> 6, lane = tid & 63;
    const int lr = lane & 15, g = lane >> 4;
    f32x4 acc[4];
#pragma unroll
    for (int t = 0; t < 4; ++t) acc[t] = (f32x4){0.f, 0.f, 0.f, 0.f};
    const int nchk = (NE + 63) >> 6;
    for (int ch = blockIdx.x; ch < nchk; ch += gridDim.x) {
        int r0 = ch * 64;
        __syncthreads();   // previous iteration's readers done
#pragma unroll
        for (int q = 0; q < 4; ++q) {
            int f = q * 256 + tid;
            int pl = f >> 9, rem = f & 511;
            int row = rem >> 3, cc = rem & 7;
            int rr = r0 + row;
            us8 v = (us8){0, 0, 0, 0, 0, 0, 0, 0};
            if (rr < NE) v = *(const us8*)(e1s + (size_t)rr * 128 + pl * 64 + cc * 8);
            unsigned short* dstp = pl ? TL : TH;
#pragma unroll
            for (int j = 0; j < 8; ++j) dstp[(cc * 8 + j) * GP + row] = v[j];
        }
        __syncthreads();
#pragma unroll
        for (int kk = 0; kk < 2; ++kk) {
            int k0 = kk * 32 + g * 8;
            b16x8 ah = ldfrag(TH, (wv * 16 + lr) * GP + k0);
            b16x8 al = ldfrag(TL, (wv * 16 + lr) * GP + k0);
#pragma unroll
            for (int b = 0; b < 4; ++b) {
                b16x8 bh = ldfrag(TH, (b * 16 + lr) * GP + k0);
                b16x8 bl = ldfrag(TL, (b * 16 + lr) * GP + k0);
                acc[b] = MF(ah, bh, acc[b]);
                acc[b] = MF(ah, bl, acc[b]);
                acc[b] = MF(al, bh, acc[b]);
            }
        }
    }
#pragma unroll
    for (int b = 0; b < 4; ++b)
#pragma unroll
        for (int r = 0; r < 4; ++r) {
            int row = wv * 16 + g * 4 + r;
            int col = b * 16 + lr;
            atomicAdd(&G[row * 64 + col], acc[b][r]);
        }
}

// ---------------- CSR build ----------------
__global__ void k_hist(const int* __restrict__ dst_t, const int* __restrict__ dst_n, int* __restrict__ hist) {
    int e = blockIdx.x * 256 + threadIdx.x;
    if (e < NE && dst_t[e] == 1) atomicAdd(&hist[dst_n[e]], 1);
}

__global__ __launch_bounds__(1024) void k_scan(const int* __restrict__ hist, int* __restrict__ row_start) {
    __shared__ int part[1024];
    const int tid = threadIdx.x;
    const int chunk = (NOUT + 1023) / 1024;
    int lo = tid * chunk, hi = min(lo + chunk, NOUT);
    int s = 0;
    for (int i = lo; i < hi; ++i) s += hist[i];
    part[tid] = s;
    __syncthreads();
    for (int off = 1; off < 1024; off <<= 1) {
        int v = part[tid];
        int add = (tid >= off) ? part[tid - off] : 0;
        __syncthreads();
        part[tid] = v + add;
        __syncthreads();
    }
    int base = (tid == 0) ? 0 : part[tid - 1];
    for (int i = lo; i < hi; ++i) { row_start[i] = base; base += hist[i]; }
    if (lo < NOUT && hi == NOUT) row_start[NOUT] = base;
}

__global__ void k_scatter(const int* __restrict__ dst_t, const int* __restrict__ dst_n,
                          const int* __restrict__ row_start, int* __restrict__ cursor, int* __restrict__ elist) {
    int e = blockIdx.x * 256 + threadIdx.x;
    if (e < NE && dst_t[e] == 1) {
        int n = dst_n[e];
        int pos = atomicAdd(&cursor[n], 1);
        elist[row_start[n] + pos] = e;
    }
}

// ---------------- logits for VALID edges (MFMA; A = e1s frags, B = G image) ----------------
__global__ __launch_bounds__(512, 4) void k_logits_c(const unsigned short* __restrict__ e1s,
                                                     const unsigned short* __restrict__ wimg,
                                                     const int* __restrict__ row_start,
                                                     const int* __restrict__ elist,
                                                     float* __restrict__ lgc) {
    __shared__ unsigned short XH[8192], XL[8192], WHL[8192];
    const int tid = threadIdx.x;
    const int NV = row_start[NOUT];
    const int i0 = blockIdx.x * 128;
    if (i0 >= NV) return;
    const int rmax = min(128, NV - i0);
    const int w = tid >> 6, lane = tid & 63;
    const int wr = w >> 1, wc = w & 1;

    stageWimg(wimg + (size_t)GIMG_ID * 8192, WHL, tid);
    stageX_elist(e1s, elist, i0, rmax, XH, XL, tid);
    __syncthreads();
    f32x4 acc[2][2];
    zacc(acc); mf_gemm64(XH, XL, WHL, WHL + 4096, acc, wr, wc, lane);
    writeglob_nb(acc, lgc + (size_t)i0 * 64, rmax, wr, wc, lane);
}

// ---------------- segment softmax + weighted sum (single-pass online) ----------------
__global__ __launch_bounds__(256) void k_att(const float* __restrict__ lgc, const unsigned short* __restrict__ e1s,
                                             const int* __restrict__ row_start, const int* __restrict__ elist,
                                             unsigned short* __restrict__ nfo) {
    int n = blockIdx.x * 4 + (threadIdx.x >> 6);
    int lane = threadIdx.x & 63;
    if (n >= NOUT) return;
    int s = row_start[n], t = row_start[n + 1];
    float m = -3.0e38f, den = 0.f, num = 0.f;
    for (int i = s; i < t; ++i) {
        int eid = elist[i];
        float x = lgc[(size_t)i * 64 + lane];
        float e = bf2f(e1s[(size_t)eid * 128 + lane]) + bf2f(e1s[(size_t)eid * 128 + 64 + lane]);
        float mn = fmaxf(m, x);
        float sc = __expf(m - mn);
        float ex = __expf(x - mn);
        den = fmaf(den, sc, ex);
        num = fmaf(num, sc, ex * e);
        m = mn;
    }
    float v = (t > s) ? num / den : 0.f;
    unsigned short h, l;
    split2t(v, h, l);   // NFO feeds only k_fuse picks (non-accumulating) — trunc ok
    nfo[(size_t)n * 128 + lane] = h;
    nfo[(size_t)n * 128 + 64 + lane] = l;
}

// ---------------- fused: self-L1 front-loaded + ef2 chain + self chain + score -> out ----------------
// Conservative barrier discipline (R6-verified). e1s read ONCE (prologue); self-L1 (accS)
// runs on those planes before the ef2 channel loop overwrites them. FAST numerics
// (approx gelu, trunc split) are safe here: this kernel is outside the Gram path.
__global__ __launch_bounds__(512, 4) void k_fuse(
    const unsigned short* __restrict__ e1s, const unsigned short* __restrict__ nfo,
    const unsigned short* __restrict__ wimg, const float* __restrict__ volt,
    const int* __restrict__ src_t, const int* __restrict__ src_n,
    const int* __restrict__ dst_t, const int* __restrict__ dst_n,
    const int* __restrict__ vg_t, const int* __restrict__ vg_i,
    const int* __restrict__ vb_t, const int* __restrict__ vb_i,
    const float* __restrict__ nf1W, const float* __restrict__ nf1b,
    const float* __restrict__ mb1, const float* __restrict__ mb2,
    const float* __restrict__ mb3, const float* __restrict__ mb4,
    const float* __restrict__ rb1, const float* __restrict__ rb2,
    const float* __restrict__ rb3, const float* __restrict__ rb4,
    const float* __restrict__ selb1, const float* __restrict__ selb2,
    const float* __restrict__ selb3, const float* __restrict__ selb4,
    const float* __restrict__ scb, float* __restrict__ out) {
    __shared__ unsigned short XH[8192], XL[8192], WHL[8192];
    __shared__ float sb[3][64], sNW[64], sNB[64];
    const int tid = threadIdx.x;
    const int gy = blockIdx.y;
    const bool mos = gy < 2;
    const int ty = mos ? gy : gy - 2;
    const int nch = mos ? 5 : 3;
    const int i0 = blockIdx.x * 128;
    const int rmax = min(128, EP - i0);
    const int w = tid >> 6, lane = tid & 63;
    const int wr = w >> 1, wc = w & 1;
    const int lr = lane & 15;
    const int erow0 = (mos ? 0 : M2) + ty * EP + i0;
    const int w1base = mos ? 10 + ty * 5 : 26 + ty * 3;
    const int w2img = mos ? 20 + ty : 35 + ty;
    const int w3img = mos ? 22 + ty : 38 + ty;
    const int w4img = mos ? 24 + ty : 41 + ty;
    const float* b1 = mos ? mb1 : rb1;
    const float* b2 = mos ? mb2 : rb2;
    const float* b3 = mos ? mb3 : rb3;
    const float* b4 = mos ? mb4 : rb4;

    // ---- prologue: selfW1 image + e1s planes (single global read of e1s) ----
    stageWimg(wimg + (size_t)44 * 8192, WHL, tid);
    stageX_rows(e1s + (size_t)erow0 * 128, rmax, XH, XL, tid);
    if (tid < 64) sNW[tid] = nf1W[tid];
    else if (tid < 128) sNB[tid - 64] = nf1b[tid - 64];
    else if (tid < 192) sb[0][tid - 128] = b1[ty * 64 + tid - 128];
    __syncthreads();

    f32x4 acc[2][2], accS[2][2], ef2r[2][2];
    zacc(accS);
    mf_gemm64(XH, XL, WHL, WHL + 4096, accS, wr, wc, lane);   // self L1 (parked in regs)
    __syncthreads();                                          // all waves done reading WHL
    stageWimg(wimg + (size_t)w1base * 8192, WHL, tid);        // ef2 W1 channel 0
    __syncthreads();
    zacc(acc);
    mf_gemm64(XH, XL, WHL, WHL + 4096, acc, wr, wc, lane);    // ef2 L1 c0 (same planes)
    // ---- ef2 L1 channels 1..nch-1 ----
    for (int c = 1; c < nch; ++c) {
        __syncthreads();
        stageWimg(wimg + (size_t)(w1base + c) * 8192, WHL, tid);
        if (c == 1) stageX_pick(src_t, src_n, erow0, rmax, volt, nfo, sNW, sNB, XH, XL, tid);
        else if (c == 2) stageX_pick(dst_t, dst_n, erow0, rmax, volt, nfo, sNW, sNB, XH, XL, tid);
        else if (c == 3) stageX_pick(vg_t, vg_i, erow0, rmax, volt, nfo, sNW, sNB, XH, XL, tid);
        else stageX_pick(vb_t, vb_i, erow0, rmax, volt, nfo, sNW, sNB, XH, XL, tid);
        __syncthreads();
        mf_gemm64(XH, XL, WHL, WHL + 4096, acc, wr, wc, lane);
    }
    // ---- ef2 L2..L4 ----
    __syncthreads();
    writeback<true, true>(acc, sb[0], XH, XL, wr, wc, lane);  // gelu(+b1)
    stageWimg(wimg + (size_t)w2img * 8192, WHL, tid);
    if (tid < 64) sb[1][tid] = b2[ty * 64 + tid];
    __syncthreads();
    zacc(acc); mf_gemm64(XH, XL, WHL, WHL + 4096, acc, wr, wc, lane);
    __syncthreads();
    writeback<true, true>(acc, sb[1], XH, XL, wr, wc, lane);
    stageWimg(wimg + (size_t)w3img * 8192, WHL, tid);
    if (tid < 64) sb[2][tid] = b3[ty * 64 + tid];
    __syncthreads();
    zacc(acc); mf_gemm64(XH, XL, WHL, WHL + 4096, acc, wr, wc, lane);
    __syncthreads();
    writeback<true, true>(acc, sb[2], XH, XL, wr, wc, lane);
    stageWimg(wimg + (size_t)w4img * 8192, WHL, tid);
    if (tid < 64) sb[0][tid] = b4[ty * 64 + tid];
    else if (tid < 128) sb[1][tid - 64] = selb1[tid - 64];
    __syncthreads();
    zacc(acc); mf_gemm64(XH, XL, WHL, WHL + 4096, acc, wr, wc, lane);   // ef2 L4
    // ef2 result (with bias b4) held in registers
#pragma unroll
    for (int rt = 0; rt < 2; ++rt)
#pragma unroll
        for (int t = 0; t < 2; ++t)
#pragma unroll
            for (int r = 0; r < 4; ++r)
                ef2r[rt][t][r] = acc[rt][t][r] + sb[0][(wc * 2 + t) * 16 + lr];
    __syncthreads();   // all waves done reading planes/WHL
    // ---- self L2..L4: accS -> planes (gelu+selb1), then chain ----
    writeback<true, true>(accS, sb[1], XH, XL, wr, wc, lane);
    stageWimg(wimg + (size_t)45 * 8192, WHL, tid);
    if (tid < 64) sb[2][tid] = selb2[tid];
    __syncthreads();
    zacc(acc); mf_gemm64(XH, XL, WHL, WHL + 4096, acc, wr, wc, lane);
    __syncthreads();
    writeback<true, true>(acc, sb[2], XH, XL, wr, wc, lane);
    stageWimg(wimg + (size_t)46 * 8192, WHL, tid);
    if (tid < 64) sb[0][tid] = selb3[tid];
    __syncthreads();
    zacc(acc); mf_gemm64(XH, XL, WHL, WHL + 4096, acc, wr, wc, lane);
    __syncthreads();
    writeback<true, true>(acc, sb[0], XH, XL, wr, wc, lane);
    stageWimg(wimg + (size_t)47 * 8192, WHL, tid);
    if (tid < 64) sb[1][tid] = selb4[tid];
    __syncthreads();
    zacc(acc); mf_gemm64(XH, XL, WHL, WHL + 4096, acc, wr, wc, lane);   // self L4
    __syncthreads();
    // z = selfL4 + selb4 + ef2r -> planes (no gelu); stage score weights
    {
        int g = lane >> 4;
#pragma unroll
        for (int rt = 0; rt < 2; ++rt)
#pragma unroll
            for (int t = 0; t < 2; ++t)
#pragma unroll
                for (int r = 0; r < 4; ++r) {
                    int row = wr * 32 + rt * 16 + g * 4 + r;
                    int col = (wc * 2 + t) * 16 + lr;
                    float v = acc[rt][t][r] + sb[1][col] + ef2r[rt][t][r];
                    unsigned short h, l;
                    split2t(v, h, l);
                    int id = xidx(row, col);
                    XH[id] = h; XL[id] = l;
                }
    }
    stageWimg(wimg + (size_t)48 * 8192, WHL, tid);
    if (tid < 64) sb[2][tid] = scb[tid];
    __syncthreads();
    zacc(acc); mf_gemm64(XH, XL, WHL, WHL + 4096, acc, wr, wc, lane);   // score
    writeglob(acc, sb[2], out + (size_t)erow0 * 64, rmax, wr, wc, lane);
}

extern "C" void kernel_launch(void* const* d_in, const int* in_sizes, int n_in,
                              void* d_out, int out_size, void* d_ws, size_t ws_size,
                              hipStream_t stream) {
    const float* volt = (const float*)d_in[0];
    const float* dp   = (const float*)d_in[1];
    const int* src_t  = (const int*)d_in[2];
    const int* dst_t  = (const int*)d_in[3];
    const int* src_n  = (const int*)d_in[4];
    const int* dst_n  = (const int*)d_in[5];
    const int* vg_t   = (const int*)d_in[6];
    const int* vg_i   = (const int*)d_in[7];
    const int* vb_t   = (const int*)d_in[8];
    const int* vb_i   = (const int*)d_in[9];
    const float* nf1W = (const float*)d_in[11];
    const float* nf1b = (const float*)d_in[12];
    const float* e1W1 = (const float*)d_in[13];
    const float* e1b1 = (const float*)d_in[14];
    const float* e1W2 = (const float*)d_in[15];
    const float* e1b2 = (const float*)d_in[16];
    const float* e1W3 = (const float*)d_in[17];
    const float* e1b3 = (const float*)d_in[18];
    const float* mW1 = (const float*)d_in[19];  const float* mb1 = (const float*)d_in[20];
    const float* mW2 = (const float*)d_in[21];  const float* mb2 = (const float*)d_in[22];
    const float* mW3 = (const float*)d_in[23];  const float* mb3 = (const float*)d_in[24];
    const float* mW4 = (const float*)d_in[25];  const float* mb4 = (const float*)d_in[26];
    const float* rW1 = (const float*)d_in[27];  const float* rb1 = (const float*)d_in[28];
    const float* rW2 = (const float*)d_in[29];  const float* rb2 = (const float*)d_in[30];
    const float* rW3 = (const float*)d_in[31];  const float* rb3 = (const float*)d_in[32];
    const float* rW4 = (const float*)d_in[33];  const float* rb4 = (const float*)d_in[34];
    const float* selW1 = (const float*)d_in[35]; const float* selb1 = (const float*)d_in[36];
    const float* selW2 = (const float*)d_in[37]; const float* selb2 = (const float*)d_in[38];
    const float* selW3 = (const float*)d_in[39]; const float* selb3 = (const float*)d_in[40];
    const float* selW4 = (const float*)d_in[41]; const float* selb4 = (const float*)d_in[42];
    const float* scW = (const float*)d_in[43];   const float* scb = (const float*)d_in[44];

    // ws layout: lgc f32 | NFO | WIMG(50) | G | ints ; E1S table lives in d_out
    float* lgc = (float*)d_ws;
    unsigned short* NFO  = (unsigned short*)(lgc + (size_t)NE * 64);
    unsigned short* WIMG = NFO + (size_t)NOUT * 128;
    float* G = (float*)(WIMG + (size_t)(NIMG + 1) * 8192);
    int* hist      = (int*)(G + 4096);
    int* cursor    = hist + NOUT;
    int* row_start = cursor + NOUT;
    int* elist     = row_start + NOUT + 1;
    unsigned short* E1S = (unsigned short*)d_out;

    const int T128_EP = (EP + 127) / 128;   // 469
    const int T128_E  = (NE + 127) / 128;   // 2344
    const int nz = 4096 + NOUT + NOUT;      // G + hist + cursor (contiguous)
    const int ZB = (nz + 255) / 256;        // 407 zeroing blocks
    dim3 b256(256), b512(512);

    k_prepw<<<NIMG + ZB, b256, 0, stream>>>(e1W2, e1W3, mW1, mW2, mW3, mW4,
                                            rW1, rW2, rW3, rW4, selW1, selW2, selW3, selW4, scW,
                                            WIMG, (int*)G, nz);
    k_ef1<<<dim3(T128_EP, 5), b512, 0, stream>>>(dp, e1W1, e1b1, e1b2, e1b3, WIMG, E1S);
    k_hist<<<(NE + 255) / 256, b256, 0, stream>>>(dst_t, dst_n, hist);
    k_scan<<<1, 1024, 0, stream>>>(hist, row_start);
    k_scatter<<<(NE + 255) / 256, b256, 0, stream>>>(dst_t, dst_n, row_start, cursor, elist);
    k_gram<<<640, b256, 0, stream>>>(E1S, G);
    k_prepg<<<1, b256, 0, stream>>>(G, WIMG);
    k_logits_c<<<T128_E, b512, 0, stream>>>(E1S, WIMG, row_start, elist, lgc);
    k_att<<<NOUT / 4, b256, 0, stream>>>(lgc, E1S, row_start, elist, NFO);
    k_fuse<<<dim3(T128_EP, 5), b512, 0, stream>>>(E1S, NFO, WIMG, volt,
        src_t, src_n, dst_t, dst_n, vg_t, vg_i, vb_t, vb_i, nf1W, nf1b,
        mb1, mb2, mb3, mb4, rb1, rb2, rb3, rb4,
        selb1, selb2, selb3, selb4, scb, (float*)d_out);
}